// Round 5
// baseline (3911.428 us; speedup 1.0000x reference)
//
#include <hip/hip_runtime.h>
#include <cstdint>
#include <cstddef>

typedef __attribute__((ext_vector_type(8))) short short8;
typedef __attribute__((ext_vector_type(4))) short short4v;
typedef __attribute__((ext_vector_type(4))) float f32x4;
typedef __attribute__((ext_vector_type(16))) float f32x16;

#define DEV __device__ __forceinline__

// Problem geometry (fixed by the reference)
constexpr int DD = 2048;           // D
constexpr int HHID = 8192;         // H
constexpr int BB = 4;              // B
constexpr int SS = 2048;           // S
constexpr size_t NX = (size_t)BB * SS * DD;   // 16,777,216
constexpr size_t NW = (size_t)DD * HHID;      // 16,777,216
constexpr size_t NH = (size_t)BB * SS * HHID; // 67,108,864

// Scratch layout (bytes)
constexpr size_t OFF_XH = 0;
constexpr size_t OFF_XL = OFF_XH + NX * 2;
constexpr size_t OFF_WH = OFF_XL + NX * 2;
constexpr size_t OFF_WL = OFF_WH + NW * 2;
constexpr size_t OFF_HH = OFF_WL + NW * 2;   // 128 MiB region
constexpr size_t OFF_HL = OFF_HH + NH * 2;   // 128 MiB region
constexpr size_t OFF_QH = OFF_HL + NH * 2;
constexpr size_t OFF_QL = OFF_QH + NX * 2;
constexpr size_t OFF_KH = OFF_QL + NX * 2;
constexpr size_t OFF_KL = OFF_KH + NX * 2;
constexpr size_t OFF_V  = OFF_KL + NX * 2;
constexpr size_t WS_TOTAL = OFF_V + NX * 2;  // ~570 MB
constexpr size_t OFF_ST = OFF_HH;            // fp32 scores^T
constexpr size_t OFF_PT = OFF_HL;            // bf16 probs^T

__device__ __align__(256) unsigned char g_ws[WS_TOTAL];

DEV unsigned char* wsbase(unsigned char* p) { return p ? p : (unsigned char*)g_ws; }
DEV short f2bf(float v) { __bf16 b = (__bf16)v; return __builtin_bit_cast(short, b); }
DEV float bf2f(short s) { return (float)__builtin_bit_cast(__bf16, s); }

DEV void gl16(const short* g, short* l) {
  __builtin_amdgcn_global_load_lds((const __attribute__((address_space(1))) void*)g,
                                   (__attribute__((address_space(3))) void*)l, 16, 0, 0);
}

// ---------------------------------------------------------------------------
// split cast: fp32 -> (hi, lo) bf16
// ---------------------------------------------------------------------------
__global__ void split_cast_k(const float* __restrict__ x, unsigned char* wsb,
                             size_t oh, size_t ol, size_t n4) {
  unsigned char* ws = wsbase(wsb);
  short4v* OH = (short4v*)(ws + oh);
  short4v* OL = (short4v*)(ws + ol);
  const f32x4* X = (const f32x4*)x;
  for (size_t i = (size_t)blockIdx.x * blockDim.x + threadIdx.x; i < n4;
       i += (size_t)gridDim.x * blockDim.x) {
    const f32x4 v = X[i];
    short4v hs, ls;
#pragma unroll
    for (int e = 0; e < 4; ++e) {
      const short hb = f2bf(v[e]);
      hs[e] = hb;
      ls[e] = f2bf(v[e] - bf2f(hb));
    }
    OH[i] = hs;
    OL[i] = ls;
  }
}

// ---------------------------------------------------------------------------
// transpose + (split-)cast: src R x C fp32 -> out C x R bf16 hi[/lo]
// ---------------------------------------------------------------------------
__global__ void transpose_cast_k(const float* __restrict__ src, unsigned char* wsb,
                                 size_t oh, size_t ol, int R, int C, int do_split) {
  __shared__ float t[32][33];
  unsigned char* ws = wsbase(wsb);
  short* OH = (short*)(ws + oh);
  short* OL = (short*)(ws + ol);
  const int c0 = blockIdx.x << 5, r0 = blockIdx.y << 5;
  const int x = threadIdx.x, y = threadIdx.y;
#pragma unroll
  for (int i = 0; i < 4; ++i) {
    const int rr = y + (i << 3);
    t[rr][x] = src[(size_t)(r0 + rr) * C + c0 + x];
  }
  __syncthreads();
#pragma unroll
  for (int i = 0; i < 4; ++i) {
    const int oc = y + (i << 3);
    const float v = t[x][oc];
    const size_t o = (size_t)(c0 + oc) * R + r0 + x;
    const short hb = f2bf(v);
    OH[o] = hb;
    if (do_split) OL[o] = f2bf(v - bf2f(hb));
  }
}

// ---------------------------------------------------------------------------
// 256x256-tile 8-wave GEMM on 32x32x16 MFMA, ONE barrier + ONE counted vmcnt
// per K-tile. A triple-buffered (3 x 32KB), B double-buffered (2 x 32KB) =
// 160 KiB LDS. Per tile t: vmcnt(4) [waits A(t),B(t); leaves A(t+2) in
// flight] -> barrier -> issue B(t+1), A(t+2) -> {24 ds_read interleaved with
// 48 MFMA in one scheduling region}.
// C[m][n] = sum_k A[m][k] * BT[n][k].  NAB=1: plain bf16, BK=64.
// NAB=2: split hi/lo bf16 (3 MFMA terms), BK=32.
// STORE: 0 split-bf16 out (LDS-bounce), 1 bf16 out (LDS-bounce),
//        2 fp32 transposed scratch (LDS-transpose bounce), 3 fp32 optr bounce.
// ---------------------------------------------------------------------------
constexpr int SLOT = 16384;   // shorts per 32KB slot

DEV f32x16 mfma32(short8 a, short8 b, f32x16 c) {
  return __builtin_amdgcn_mfma_f32_32x32x16_bf16(a, b, c, 0, 0, 0);
}

// NAB==1 slot: [256][64] shorts; granule g = s*2+lh (s:kstep 0..3), swz ^ (row&7)
DEV short8 rf1(const short* slot, int row, int s, int lh) {
  return *(const short8*)&slot[row * 64 + ((((s << 1) | lh) ^ (row & 7)) << 3)];
}
// NAB==2 slot: two chunks [256][32]; c=0 hi, c=1 lo; g = s*2+lh (s 0..1),
// swz ^ ((row>>1)&3)
DEV short8 rf2(const short* slot, int c, int row, int s, int lh) {
  return *(const short8*)&slot[c * 8192 + row * 32 + ((((s << 1) | lh) ^ ((row >> 1) & 3)) << 3)];
}

template <int NAB, bool RELU, int STORE>
__launch_bounds__(512, 2)
__global__ void gemm32_k(unsigned char* wsb,
                         size_t aoff0, size_t aoff1, size_t boff0, size_t boff1,
                         const float* __restrict__ bias,
                         size_t ooff0, size_t ooff1, float* __restrict__ optr,
                         int M, int N, int K, int gx, int gxy) {
  constexpr int BK = (NAB == 2) ? 32 : 64;
  // LDS: A slots {0,1,2}*SLOT ; B slots {3,4}*SLOT. 5*SLOT*2B = 160 KiB.
  __shared__ alignas(16) short lds[5 * SLOT];

  unsigned char* ws = wsbase(wsb);
  const int tid = threadIdx.x;
  const int lane = tid & 63;
  const int wave = tid >> 6;
  const int wm = (wave >> 2) << 7;   // 0 / 128
  const int wn = (wave & 3) << 6;    // 0 / 64 / 128 / 192
  const int rl = lane & 31;
  const int lh = lane >> 5;

  // bijective XCD swizzle (all grids are multiples of 8)
  const int nwg = gridDim.x;
  const int q8 = nwg >> 3;
  const int id = (blockIdx.x & 7) * q8 + (blockIdx.x >> 3);
  const int bz = id / gxy;
  const int rem = id - bz * gxy;
  const int by = rem / gx;
  const int bx = rem - by * gx;
  const int brow = by << 8;
  const int bcol = bx << 8;

  const size_t batchA = (size_t)bz * M * K;
  const size_t batchB = (size_t)bz * N * K;
  const short* A0 = (const short*)(ws + aoff0) + batchA;
  const short* A1 = (const short*)(ws + aoff1) + batchA;
  const short* B0g = (const short*)(ws + boff0) + batchB;
  const short* B1g = (const short*)(ws + boff1) + batchB;

  // per-thread staging source offsets (granule-swizzled)
  int aOff[4], bOff[4];
  if constexpr (NAB == 1) {
#pragma unroll
    for (int h = 0; h < 4; ++h) {
      const int G = tid + h * 512;
      const int r = G >> 3, c = G & 7;
      aOff[h] = (brow + r) * K + ((c ^ (r & 7)) << 3);
      bOff[h] = (bcol + r) * K + ((c ^ (r & 7)) << 3);
    }
  } else {
#pragma unroll
    for (int h = 0; h < 2; ++h) {
      const int G = tid + h * 512;
      const int r = G >> 2, c = G & 3;
      aOff[h] = (brow + r) * K + ((c ^ ((r >> 1) & 3)) << 3);
      bOff[h] = (bcol + r) * K + ((c ^ ((r >> 1) & 3)) << 3);
    }
  }

  auto stageA = [&](int slotBase, int tt) {   // 4 gl16
    const size_t ka = (size_t)tt * BK;
    if constexpr (NAB == 1) {
#pragma unroll
      for (int h = 0; h < 4; ++h)
        gl16(A0 + aOff[h] + ka, &lds[slotBase + ((tid + h * 512) << 3)]);
    } else {
#pragma unroll
      for (int h = 0; h < 2; ++h) {
        gl16(A0 + aOff[h] + ka, &lds[slotBase + ((tid + h * 512) << 3)]);
        gl16(A1 + aOff[h] + ka, &lds[slotBase + 8192 + ((tid + h * 512) << 3)]);
      }
    }
  };
  auto stageB = [&](int slotBase, int tt) {   // 4 gl16
    const size_t ka = (size_t)tt * BK;
    if constexpr (NAB == 1) {
#pragma unroll
      for (int h = 0; h < 4; ++h)
        gl16(B0g + bOff[h] + ka, &lds[slotBase + ((tid + h * 512) << 3)]);
    } else {
#pragma unroll
      for (int h = 0; h < 2; ++h) {
        gl16(B0g + bOff[h] + ka, &lds[slotBase + ((tid + h * 512) << 3)]);
        gl16(B1g + bOff[h] + ka, &lds[slotBase + 8192 + ((tid + h * 512) << 3)]);
      }
    }
  };

  const int nt = K / BK;
  f32x16 acc[4][2] = {};   // [i2 row-32-tile][j2 col-32-tile]

  // prologue: A(0)->slot0, B(0)->Bslot0, A(1)->slot1  (order matters for vmcnt)
  stageA(0, 0);
  stageB(3 * SLOT, 0);
  if (nt > 1) stageA(SLOT, 1);

  int saCur = 0;     // A slot of tile t
  int saStage = 2;   // A slot for tile t+2
  int sbCur = 0;     // B slot of tile t (0/1)

  for (int t = 0; t < nt; ++t) {
    if (t + 1 < nt) {
      asm volatile("s_waitcnt vmcnt(4)" ::: "memory");
    } else {
      asm volatile("s_waitcnt vmcnt(0)" ::: "memory");
    }
    __builtin_amdgcn_s_barrier();
    if (t + 1 < nt) stageB((3 + (sbCur ^ 1)) * SLOT, t + 1);
    if (t + 2 < nt) stageA(saStage * SLOT, t + 2);

    const short* aS = &lds[saCur * SLOT];
    const short* bS = &lds[(3 + sbCur) * SLOT];

    if constexpr (NAB == 2) {
      short8 bf[2][2][2];   // [j2][s][hi/lo]
#pragma unroll
      for (int j2 = 0; j2 < 2; ++j2)
#pragma unroll
        for (int s = 0; s < 2; ++s)
#pragma unroll
          for (int c = 0; c < 2; ++c)
            bf[j2][s][c] = rf2(bS, c, wn + j2 * 32 + rl, s, lh);
#pragma unroll
      for (int half = 0; half < 2; ++half) {
        short8 af[2][2][2];   // [il][s][hi/lo]
#pragma unroll
        for (int il = 0; il < 2; ++il)
#pragma unroll
          for (int s = 0; s < 2; ++s)
#pragma unroll
            for (int c = 0; c < 2; ++c)
              af[il][s][c] = rf2(aS, c, wm + (half * 2 + il) * 32 + rl, s, lh);
        __builtin_amdgcn_s_setprio(1);
#pragma unroll
        for (int il = 0; il < 2; ++il)
#pragma unroll
          for (int j2 = 0; j2 < 2; ++j2)
#pragma unroll
            for (int s = 0; s < 2; ++s) {
              f32x16 a_ = acc[half * 2 + il][j2];
              a_ = mfma32(af[il][s][0], bf[j2][s][0], a_);
              a_ = mfma32(af[il][s][0], bf[j2][s][1], a_);
              a_ = mfma32(af[il][s][1], bf[j2][s][0], a_);
              acc[half * 2 + il][j2] = a_;
            }
        __builtin_amdgcn_s_setprio(0);
      }
    } else {
      short8 bf[2][4];   // [j2][kstep]
#pragma unroll
      for (int j2 = 0; j2 < 2; ++j2)
#pragma unroll
        for (int s = 0; s < 4; ++s)
          bf[j2][s] = rf1(bS, wn + j2 * 32 + rl, s, lh);
#pragma unroll
      for (int half = 0; half < 2; ++half) {
        short8 af[2][4];
#pragma unroll
        for (int il = 0; il < 2; ++il)
#pragma unroll
          for (int s = 0; s < 4; ++s)
            af[il][s] = rf1(aS, wm + (half * 2 + il) * 32 + rl, s, lh);
        __builtin_amdgcn_s_setprio(1);
#pragma unroll
        for (int il = 0; il < 2; ++il)
#pragma unroll
          for (int j2 = 0; j2 < 2; ++j2)
#pragma unroll
            for (int s = 0; s < 4; ++s)
              acc[half * 2 + il][j2] = mfma32(af[il][s], bf[j2][s], acc[half * 2 + il][j2]);
        __builtin_amdgcn_s_setprio(0);
      }
    }

    saCur = (saCur == 2) ? 0 : saCur + 1;
    saStage = (saStage == 2) ? 0 : saStage + 1;
    sbCur ^= 1;
  }

  // ---- epilogue (LDS reused as bounce; loop already drained vmcnt) ----
  if constexpr (STORE == 0 || STORE == 1) {
    short* Oh = (short*)(ws + ooff0);
    short* Ol = (short*)(ws + ooff1);
    constexpr int ROUNDS = (STORE == 0) ? 2 : 1;
#pragma unroll
    for (int rd = 0; rd < ROUNDS; ++rd) {
      __builtin_amdgcn_s_barrier();
#pragma unroll
      for (int i2 = 0; i2 < 4; ++i2)
#pragma unroll
        for (int j2 = 0; j2 < 2; ++j2) {
          const int col = wn + j2 * 32 + rl;
          const float bv = bias ? bias[bcol + col] : 0.0f;
#pragma unroll
          for (int r = 0; r < 16; ++r) {
            const int row = wm + i2 * 32 + (r & 3) + ((r >> 2) << 3) + (lh << 2);
            float u = acc[i2][j2][r] + bv;
            if constexpr (RELU) u = fmaxf(u, 0.0f);
            short v;
            if (rd == 0) {
              v = f2bf(u);
            } else {
              const short hb = f2bf(u);
              v = f2bf(u - bf2f(hb));
            }
            lds[row * 264 + col] = v;
          }
        }
      __builtin_amdgcn_s_barrier();
      short* gout = (rd == 0) ? Oh : Ol;
#pragma unroll
      for (int gi = 0; gi < 16; ++gi) {
        const int g = gi * 512 + tid;
        const int row = g >> 5, cg = g & 31;
        const short8 v = *(const short8*)&lds[row * 264 + cg * 8];
        *(short8*)&gout[(size_t)(brow + row) * N + bcol + cg * 8] = v;
      }
    }
  } else if constexpr (STORE == 2) {
    // transposed fp32 scratch: bounce per column-half, f32x4 row-quads
    float* Of = (float*)(ws + ooff0) + (size_t)bz * M * N;
    float* ldsf = (float*)lds;
#pragma unroll
    for (int h = 0; h < 2; ++h) {
      __builtin_amdgcn_s_barrier();
      if ((wn >> 7) == h) {
#pragma unroll
        for (int i2 = 0; i2 < 4; ++i2)
#pragma unroll
          for (int j2 = 0; j2 < 2; ++j2) {
            const int cp = (wn & 127) + j2 * 32 + rl;
#pragma unroll
            for (int q = 0; q < 4; ++q) {
              const int rbase = wm + i2 * 32 + (q << 3) + (lh << 2);
              f32x4 v;
#pragma unroll
              for (int e = 0; e < 4; ++e) v[e] = acc[i2][j2][q * 4 + e];
              *(f32x4*)&ldsf[cp * 258 + rbase] = v;
            }
          }
      }
      __builtin_amdgcn_s_barrier();
#pragma unroll
      for (int gi = 0; gi < 16; ++gi) {
        const int g = gi * 512 + tid;
        const int tr = g >> 6, tc4 = (g & 63) << 2;
        const f32x4 v = *(const f32x4*)&ldsf[tr * 258 + tc4];
        *(f32x4*)&Of[(size_t)(bcol + h * 128 + tr) * M + brow + tc4] = v;
      }
    }
  } else {
    // fp32 row-major out: bounce per row-half
    float* Op = optr + (size_t)bz * M * N;
    float* ldsf = (float*)lds;
#pragma unroll
    for (int h = 0; h < 2; ++h) {
      __builtin_amdgcn_s_barrier();
      if ((wm >> 7) == h) {
#pragma unroll
        for (int i2 = 0; i2 < 4; ++i2)
#pragma unroll
          for (int j2 = 0; j2 < 2; ++j2) {
            const int cl = wn + j2 * 32 + rl;
#pragma unroll
            for (int q = 0; q < 4; ++q) {
              const int rp = (wm & 127) + i2 * 32 + (q << 3) + (lh << 2);
#pragma unroll
              for (int e = 0; e < 4; ++e)
                ldsf[(rp + e) * 258 + cl] = acc[i2][j2][q * 4 + e];
            }
          }
      }
      __builtin_amdgcn_s_barrier();
#pragma unroll
      for (int gi = 0; gi < 16; ++gi) {
        const int g = gi * 512 + tid;
        const int tr = g >> 6, tc4 = (g & 63) << 2;
        const f32x4 v = *(const f32x4*)&ldsf[tr * 258 + tc4];
        *(f32x4*)&Op[(size_t)(brow + h * 128 + tr) * N + bcol + tc4] = v;
      }
    }
  }
}

// ---------------------------------------------------------------------------
// row softmax over ST rows (axis-1 softmax of scores), output bf16 probs^T
// ---------------------------------------------------------------------------
__launch_bounds__(256)
__global__ void softmax_rows_k(unsigned char* wsb, size_t st, size_t pt) {
  constexpr int S = 2048;
  unsigned char* ws = wsbase(wsb);
  const f32x4* row = (const f32x4*)((const float*)(ws + st) + (size_t)blockIdx.x * S);
  short4v* out = (short4v*)((short*)(ws + pt) + (size_t)blockIdx.x * S);
  const int tid = threadIdx.x, lane = tid & 63, wv = tid >> 6;
  const f32x4 a = row[tid];
  const f32x4 b = row[tid + 256];
  float m = fmaxf(fmaxf(fmaxf(a[0], a[1]), fmaxf(a[2], a[3])),
                  fmaxf(fmaxf(b[0], b[1]), fmaxf(b[2], b[3])));
#pragma unroll
  for (int o = 32; o; o >>= 1) m = fmaxf(m, __shfl_xor(m, o));
  __shared__ float rb[8];
  if (lane == 0) rb[wv] = m;
  __syncthreads();
  m = fmaxf(fmaxf(rb[0], rb[1]), fmaxf(rb[2], rb[3]));
  float e[8];
  float s = 0.0f;
#pragma unroll
  for (int q = 0; q < 4; ++q) { e[q] = expf(a[q] - m); s += e[q]; }
#pragma unroll
  for (int q = 0; q < 4; ++q) { e[4 + q] = expf(b[q] - m); s += e[4 + q]; }
#pragma unroll
  for (int o = 32; o; o >>= 1) s += __shfl_xor(s, o);
  if (lane == 0) rb[4 + wv] = s;
  __syncthreads();
  s = rb[4] + rb[5] + rb[6] + rb[7];
  const float inv = 1.0f / s;
  short4v o1, o2;
#pragma unroll
  for (int q = 0; q < 4; ++q) { o1[q] = f2bf(e[q] * inv); o2[q] = f2bf(e[4 + q] * inv); }
  out[tid] = o1;
  out[tid + 256] = o2;
}

// ---------------------------------------------------------------------------
extern "C" void kernel_launch(void* const* d_in, const int* in_sizes, int n_in,
                              void* d_out, int out_size, void* d_ws, size_t ws_size,
                              hipStream_t stream) {
  const float* x   = (const float*)d_in[0];
  const float* qw1 = (const float*)d_in[1];
  const float* qb1 = (const float*)d_in[2];
  const float* qw2 = (const float*)d_in[3];
  const float* qb2 = (const float*)d_in[4];
  const float* kw1 = (const float*)d_in[5];
  const float* kb1 = (const float*)d_in[6];
  const float* kw2 = (const float*)d_in[7];
  const float* kb2 = (const float*)d_in[8];
  const float* vw1 = (const float*)d_in[9];
  const float* vb1 = (const float*)d_in[10];
  const float* vw2 = (const float*)d_in[11];
  const float* vb2 = (const float*)d_in[12];
  float* out = (float*)d_out;
  unsigned char* wsb = (ws_size >= WS_TOTAL) ? (unsigned char*)d_ws : nullptr;

  const int M = BB * SS;  // 8192
  dim3 blk(512);
  dim3 tb(32, 8);

  // x -> hi/lo bf16
  split_cast_k<<<4096, 256, 0, stream>>>(x, wsb, OFF_XH, OFF_XL, NX / 4);

  // ---- Q path (split precision) ----
  transpose_cast_k<<<dim3(HHID / 32, DD / 32), tb, 0, stream>>>(qw1, wsb, OFF_WH, OFF_WL, DD, HHID, 1);
  gemm32_k<2, true, 0><<<1024, blk, 0, stream>>>(
      wsb, OFF_XH, OFF_XL, OFF_WH, OFF_WL, qb1, OFF_HH, OFF_HL, nullptr, M, HHID, DD, 32, 1024);
  transpose_cast_k<<<dim3(DD / 32, HHID / 32), tb, 0, stream>>>(qw2, wsb, OFF_WH, OFF_WL, HHID, DD, 1);
  gemm32_k<2, false, 0><<<256, blk, 0, stream>>>(
      wsb, OFF_HH, OFF_HL, OFF_WH, OFF_WL, qb2, OFF_QH, OFF_QL, nullptr, M, DD, HHID, 8, 256);

  // ---- K path (split precision) ----
  transpose_cast_k<<<dim3(HHID / 32, DD / 32), tb, 0, stream>>>(kw1, wsb, OFF_WH, OFF_WL, DD, HHID, 1);
  gemm32_k<2, true, 0><<<1024, blk, 0, stream>>>(
      wsb, OFF_XH, OFF_XL, OFF_WH, OFF_WL, kb1, OFF_HH, OFF_HL, nullptr, M, HHID, DD, 32, 1024);
  transpose_cast_k<<<dim3(DD / 32, HHID / 32), tb, 0, stream>>>(kw2, wsb, OFF_WH, OFF_WL, HHID, DD, 1);
  gemm32_k<2, false, 0><<<256, blk, 0, stream>>>(
      wsb, OFF_HH, OFF_HL, OFF_WH, OFF_WL, kb2, OFF_KH, OFF_KL, nullptr, M, DD, HHID, 8, 256);

  // ---- V path (plain bf16) ----
  transpose_cast_k<<<dim3(HHID / 32, DD / 32), tb, 0, stream>>>(vw1, wsb, OFF_WH, OFF_WL, DD, HHID, 0);
  gemm32_k<1, true, 1><<<1024, blk, 0, stream>>>(
      wsb, OFF_XH, 0, OFF_WH, 0, vb1, OFF_HH, 0, nullptr, M, HHID, DD, 32, 1024);
  transpose_cast_k<<<dim3(DD / 32, HHID / 32), tb, 0, stream>>>(vw2, wsb, OFF_WH, OFF_WL, HHID, DD, 0);
  gemm32_k<1, false, 1><<<256, blk, 0, stream>>>(
      wsb, OFF_HH, 0, OFF_WH, 0, vb2, OFF_V, 0, nullptr, M, DD, HHID, 8, 256);

  // ---- scores^T = (Q K^T)^T per batch, split precision, fp32 ----
  gemm32_k<2, false, 2><<<256, blk, 0, stream>>>(
      wsb, OFF_QH, OFF_QL, OFF_KH, OFF_KL, nullptr, OFF_ST, 0, nullptr, SS, SS, DD, 8, 64);

  // ---- softmax over axis 1 == row softmax of ST; writes bf16 probs^T ----
  softmax_rows_k<<<BB * SS, 256, 0, stream>>>(wsb, OFF_ST, OFF_PT);

  // ---- out = V @ probs  (B^T = probs^T), fp32 to d_out ----
  gemm32_k<1, false, 3><<<256, blk, 0, stream>>>(
      wsb, OFF_V, 0, OFF_PT, 0, nullptr, 0, 0, out, SS, SS, DD, 8, 64);
}

// Round 6
// 3065.850 us; speedup vs baseline: 1.2758x; 1.2758x over previous
//
#include <hip/hip_runtime.h>
#include <cstdint>
#include <cstddef>

typedef __attribute__((ext_vector_type(8))) short short8;
typedef __attribute__((ext_vector_type(4))) short short4v;
typedef __attribute__((ext_vector_type(4))) float f32x4;
typedef __attribute__((ext_vector_type(4))) int i32x4;

#define DEV __device__ __forceinline__

// Problem geometry (fixed by the reference)
constexpr int DD = 2048;           // D
constexpr int HHID = 8192;         // H
constexpr int BB = 4;              // B
constexpr int SS = 2048;           // S
constexpr size_t NX = (size_t)BB * SS * DD;   // 16,777,216
constexpr size_t NW = (size_t)DD * HHID;      // 16,777,216
constexpr size_t NH = (size_t)BB * SS * HHID; // 67,108,864

// Scratch layout (bytes)
constexpr size_t OFF_XH = 0;
constexpr size_t OFF_XL = OFF_XH + NX * 2;   // reused: xa1 (NX) + xa2 (NX) i8
constexpr size_t OFF_WH = OFF_XL + NX * 2;
constexpr size_t OFF_WL = OFF_WH + NW * 2;   // reused: wa1 (NW) + wa2 (NW) i8
constexpr size_t OFF_HH = OFF_WL + NW * 2;   // 128 MiB region
constexpr size_t OFF_HL = OFF_HH + NH * 2;   // 128 MiB region
constexpr size_t OFF_QH = OFF_HL + NH * 2;
constexpr size_t OFF_QL = OFF_QH + NX * 2;
constexpr size_t OFF_KH = OFF_QL + NX * 2;
constexpr size_t OFF_KL = OFF_KH + NX * 2;
constexpr size_t OFF_V  = OFF_KL + NX * 2;
constexpr size_t OFF_XS  = OFF_V + NX * 2;          // f32[8192] x row scales
constexpr size_t OFF_WMQ = OFF_XS + 32768;          // u32/f32[8192] w1-col absmax (Q)
constexpr size_t OFF_WMK = OFF_WMQ + 32768;         // same (K)
constexpr size_t WS_TOTAL = OFF_WMK + 32768;
constexpr size_t OFF_ST = OFF_HH;            // fp32 scores^T
constexpr size_t OFF_PT = OFF_HL;            // bf16 probs^T
// i8 sub-offsets
constexpr size_t OFF_XA1 = OFF_XL;
constexpr size_t OFF_XA2 = OFF_XL + NX;
constexpr size_t OFF_WA1 = OFF_WL;
constexpr size_t OFF_WA2 = OFF_WL + NW;

__device__ __align__(256) unsigned char g_ws[WS_TOTAL];

DEV unsigned char* wsbase(unsigned char* p) { return p ? p : (unsigned char*)g_ws; }
DEV short f2bf(float v) { __bf16 b = (__bf16)v; return __builtin_bit_cast(short, b); }
DEV float bf2f(short s) { return (float)__builtin_bit_cast(__bf16, s); }

DEV void gl16(const short* g, short* l) {
  __builtin_amdgcn_global_load_lds((const __attribute__((address_space(1))) void*)g,
                                   (__attribute__((address_space(3))) void*)l, 16, 0, 0);
}
DEV void gl16b(const signed char* g, signed char* l) {
  __builtin_amdgcn_global_load_lds((const __attribute__((address_space(1))) void*)g,
                                   (__attribute__((address_space(3))) void*)l, 16, 0, 0);
}

// ---------------------------------------------------------------------------
// cast x -> hi bf16 (lo no longer needed: Q/K MLP1 are i8 now)
// ---------------------------------------------------------------------------
__global__ void cast_hi_k(const float* __restrict__ x, unsigned char* wsb,
                          size_t oh, size_t n4) {
  unsigned char* ws = wsbase(wsb);
  short4v* OH = (short4v*)(ws + oh);
  const f32x4* X = (const f32x4*)x;
  for (size_t i = (size_t)blockIdx.x * blockDim.x + threadIdx.x; i < n4;
       i += (size_t)gridDim.x * blockDim.x) {
    const f32x4 v = X[i];
    short4v hs;
#pragma unroll
    for (int e = 0; e < 4; ++e) hs[e] = f2bf(v[e]);
    OH[i] = hs;
  }
}

// ---------------------------------------------------------------------------
// per-row 2-level i8 quantization of x: x ~ s*(a1 + a2/256), s = rowmax/127
// ---------------------------------------------------------------------------
__launch_bounds__(256)
__global__ void quant_x_k(const float* __restrict__ x, unsigned char* wsb,
                          size_t oa1, size_t oa2, size_t oxs) {
  unsigned char* ws = wsbase(wsb);
  signed char* A1 = (signed char*)(ws + oa1);
  signed char* A2 = (signed char*)(ws + oa2);
  float* XS = (float*)(ws + oxs);
  const int row = blockIdx.x;
  const float* xr = x + (size_t)row * 2048;
  const int tid = threadIdx.x, lane = tid & 63;
  const f32x4 v0 = *(const f32x4*)&xr[tid * 8];
  const f32x4 v1 = *(const f32x4*)&xr[tid * 8 + 4];
  float m = 0.0f;
#pragma unroll
  for (int e = 0; e < 4; ++e) m = fmaxf(m, fmaxf(fabsf(v0[e]), fabsf(v1[e])));
#pragma unroll
  for (int o = 32; o; o >>= 1) m = fmaxf(m, __shfl_xor(m, o));
  __shared__ float rb[4];
  if (lane == 0) rb[tid >> 6] = m;
  __syncthreads();
  m = fmaxf(fmaxf(rb[0], rb[1]), fmaxf(rb[2], rb[3]));
  const float inv = (m > 1e-30f) ? 127.0f / m : 0.0f;
  if (tid == 0) XS[row] = m * (1.0f / 127.0f);
  unsigned int w1a = 0, w1b = 0, w2a = 0, w2b = 0;
#pragma unroll
  for (int e = 0; e < 8; ++e) {
    const float xv = (e < 4) ? v0[e] : v1[e - 4];
    const float q = xv * inv;
    const float a1f = rintf(q);
    int ia2 = (int)rintf((q - a1f) * 256.0f);
    ia2 = ia2 > 127 ? 127 : (ia2 < -127 ? -127 : ia2);
    const unsigned int b1 = (unsigned char)(signed char)(int)a1f;
    const unsigned int b2 = (unsigned char)(signed char)ia2;
    if (e < 4) { w1a |= b1 << (8 * e); w2a |= b2 << (8 * e); }
    else       { w1b |= b1 << (8 * (e - 4)); w2b |= b2 << (8 * (e - 4)); }
  }
  const size_t o = (size_t)row * 2048 + tid * 8;
  *(unsigned int*)&A1[o] = w1a; *(unsigned int*)&A1[o + 4] = w1b;
  *(unsigned int*)&A2[o] = w2a; *(unsigned int*)&A2[o + 4] = w2b;
}

// ---------------------------------------------------------------------------
// per-column absmax of w [R][C] -> MX[col] (uint-encoded float, memset to 0)
// ---------------------------------------------------------------------------
__launch_bounds__(256)
__global__ void colmax_k(const float* __restrict__ w, unsigned char* wsb,
                         size_t omax, int R, int C) {
  unsigned char* ws = wsbase(wsb);
  unsigned int* MX = (unsigned int*)(ws + omax);
  const int col = blockIdx.x * 256 + threadIdx.x;
  const int r0 = blockIdx.y * 128;
  float m = 0.0f;
  for (int r = 0; r < 128; ++r) m = fmaxf(m, fabsf(w[(size_t)(r0 + r) * C + col]));
  atomicMax(&MX[col], __float_as_uint(m));
}

// ---------------------------------------------------------------------------
// transpose + 2-level i8 quant: src R x C fp32 -> a1,a2 [C][R] i8 (per-col scale)
// ---------------------------------------------------------------------------
__global__ void transpose_quant_k(const float* __restrict__ src, unsigned char* wsb,
                                  size_t oa1, size_t oa2, size_t omax, int R, int C) {
  __shared__ float t[32][33];
  unsigned char* ws = wsbase(wsb);
  signed char* A1 = (signed char*)(ws + oa1);
  signed char* A2 = (signed char*)(ws + oa2);
  const unsigned int* MX = (const unsigned int*)(ws + omax);
  const int c0 = blockIdx.x << 5, r0 = blockIdx.y << 5;
  const int x = threadIdx.x, y = threadIdx.y;
#pragma unroll
  for (int i = 0; i < 4; ++i) {
    const int rr = y + (i << 3);
    t[rr][x] = src[(size_t)(r0 + rr) * C + c0 + x];
  }
  __syncthreads();
#pragma unroll
  for (int i = 0; i < 4; ++i) {
    const int oc = y + (i << 3);
    const float v = t[x][oc];
    const float mx = __uint_as_float(MX[c0 + oc]);
    const float inv = (mx > 1e-30f) ? 127.0f / mx : 0.0f;
    const float q = v * inv;
    const float a1f = rintf(q);
    int ia2 = (int)rintf((q - a1f) * 256.0f);
    ia2 = ia2 > 127 ? 127 : (ia2 < -127 ? -127 : ia2);
    const size_t o = (size_t)(c0 + oc) * R + r0 + x;
    A1[o] = (signed char)(int)a1f;
    A2[o] = (signed char)ia2;
  }
}

// ---------------------------------------------------------------------------
// transpose + (split-)cast: src R x C fp32 -> out C x R bf16 hi[/lo]
// ---------------------------------------------------------------------------
__global__ void transpose_cast_k(const float* __restrict__ src, unsigned char* wsb,
                                 size_t oh, size_t ol, int R, int C, int do_split) {
  __shared__ float t[32][33];
  unsigned char* ws = wsbase(wsb);
  short* OH = (short*)(ws + oh);
  short* OL = (short*)(ws + ol);
  const int c0 = blockIdx.x << 5, r0 = blockIdx.y << 5;
  const int x = threadIdx.x, y = threadIdx.y;
#pragma unroll
  for (int i = 0; i < 4; ++i) {
    const int rr = y + (i << 3);
    t[rr][x] = src[(size_t)(r0 + rr) * C + c0 + x];
  }
  __syncthreads();
#pragma unroll
  for (int i = 0; i < 4; ++i) {
    const int oc = y + (i << 3);
    const float v = t[x][oc];
    const size_t o = (size_t)(c0 + oc) * R + r0 + x;
    const short hb = f2bf(v);
    OH[o] = hb;
    if (do_split) OL[o] = f2bf(v - bf2f(hb));
  }
}

// ---------------------------------------------------------------------------
// i8 MLP1 GEMM: h[m][n] = relu(xs[m]*wm[n]/127*(I1 + I2/256) + bias[n]),
// written as split-bf16. 16x16x64 i8 MFMA, 3 terms (a1b1 -> I1; a1b2,a2b1 -> I2).
// Block tile 128x256, 8 waves of 64x64, BK=64. A 3-slot / B 2-slot LDS (112KB),
// round-4 2-phase schedule: stage A(t+2) in phase A, B(t+2) in phase B,
// counted vmcnt(6).
// ---------------------------------------------------------------------------
DEV i32x4 mfma_i8(i32x4 a, i32x4 b, i32x4 c) {
  return __builtin_amdgcn_mfma_i32_16x16x64_i8(a, b, c, 0, 0, 0);
}
DEV i32x4 rfi8(const signed char* base, int lstride, int L, int row, int fg) {
  return *(const i32x4*)&base[L * lstride + row * 64 + ((fg ^ ((row >> 1) & 3)) << 4)];
}

__launch_bounds__(512, 2)
__global__ void gemm_i8_k(unsigned char* wsb,
                          size_t xa1o, size_t xa2o, size_t wa1o, size_t wa2o,
                          size_t xso, size_t wmo, const float* __restrict__ bias,
                          size_t ohOff, size_t olOff, int M, int N, int K,
                          int gx, int gxy) {
  // LDS: A slots {0,1,2}*16KB (per slot: 2 levels x [128][64] i8),
  //      B slots {0,1} at 48KB + s*32KB (2 levels x [256][64] i8). Total 112KB.
  __shared__ alignas(16) signed char lds8[114688];

  unsigned char* ws = wsbase(wsb);
  const int tid = threadIdx.x;
  const int lane = tid & 63;
  const int wave = tid >> 6;
  const int wm = (wave >> 2) << 6;   // 0 / 64
  const int wn = (wave & 3) << 6;    // 0 / 64 / 128 / 192
  const int fr = lane & 15;
  const int fg = lane >> 4;

  // bijective XCD swizzle (nwg multiple of 8)
  const int nwg = gridDim.x;
  const int q8 = nwg >> 3;
  const int id = (blockIdx.x & 7) * q8 + (blockIdx.x >> 3);
  const int by = id / gx;
  const int bx = id - by * gx;
  const int brow = by << 7;    // 128-row tiles
  const int bcol = bx << 8;    // 256-col tiles

  const signed char* Xa1 = (const signed char*)(ws + xa1o);
  const signed char* Xa2 = (const signed char*)(ws + xa2o);
  const signed char* Wa1 = (const signed char*)(ws + wa1o);
  const signed char* Wa2 = (const signed char*)(ws + wa2o);
  const float* XS = (const float*)(ws + xso);
  const unsigned int* WM = (const unsigned int*)(ws + wmo);

  // staging source offsets (granule-swizzled, granule = 16 i8)
  const int ar = tid >> 2, ac = tid & 3;
  const size_t aOff = (size_t)(brow + ar) * K + ((ac ^ ((ar >> 1) & 3)) << 4);
  size_t bOff[2];
#pragma unroll
  for (int h = 0; h < 2; ++h) {
    const int G = tid + h * 512;
    const int r = G >> 2, c = G & 3;
    bOff[h] = (size_t)(bcol + r) * K + ((c ^ ((r >> 1) & 3)) << 4);
  }

  auto stageA = [&](int slotBase, int tt) {   // 2 gl16
    const int ko = tt * 64;
    gl16b(Xa1 + aOff + ko, &lds8[slotBase + (tid << 4)]);
    gl16b(Xa2 + aOff + ko, &lds8[slotBase + 8192 + (tid << 4)]);
  };
  auto stageB = [&](int slotBase, int tt) {   // 4 gl16
    const int ko = tt * 64;
#pragma unroll
    for (int h = 0; h < 2; ++h) {
      gl16b(Wa1 + bOff[h] + ko, &lds8[slotBase + ((tid + h * 512) << 4)]);
      gl16b(Wa2 + bOff[h] + ko, &lds8[slotBase + 16384 + ((tid + h * 512) << 4)]);
    }
  };

  const int nt = K / 64;
  i32x4 I1[4][4] = {};
  i32x4 I2[4][4] = {};

  // prologue: A0,B0,A1,B1
  stageA(0, 0);
  stageB(49152, 0);
  if (nt > 1) { stageA(16384, 1); stageB(49152 + 32768, 1); }
  if (nt > 1) { asm volatile("s_waitcnt vmcnt(6)" ::: "memory"); }
  else        { asm volatile("s_waitcnt vmcnt(0)" ::: "memory"); }
  __builtin_amdgcn_s_barrier();

  for (int t = 0; t < nt; ++t) {
    const signed char* aS = &lds8[(t % 3) * 16384];
    const signed char* bS = &lds8[49152 + (t & 1) * 32768];
    const int sA2 = ((t + 2) % 3) * 16384;
    const int sB2 = 49152 + (t & 1) * 32768;
    const bool pf = (t + 2 < nt);
    i32x4 bf[4][2], af[2][2];

    // ---- phase A: stage A(t+2); read all B frags + A rows 0-1; MFMA half 0 ----
    if (pf) stageA(sA2, t + 2);
#pragma unroll
    for (int j = 0; j < 4; ++j) {
      bf[j][0] = rfi8(bS, 16384, 0, wn + j * 16 + fr, fg);
      bf[j][1] = rfi8(bS, 16384, 1, wn + j * 16 + fr, fg);
    }
#pragma unroll
    for (int i = 0; i < 2; ++i) {
      af[i][0] = rfi8(aS, 8192, 0, wm + i * 16 + fr, fg);
      af[i][1] = rfi8(aS, 8192, 1, wm + i * 16 + fr, fg);
    }
    __builtin_amdgcn_s_setprio(1);
#pragma unroll
    for (int i = 0; i < 2; ++i)
#pragma unroll
      for (int j = 0; j < 4; ++j) {
        I1[i][j] = mfma_i8(af[i][0], bf[j][0], I1[i][j]);
        I2[i][j] = mfma_i8(af[i][0], bf[j][1], I2[i][j]);
        I2[i][j] = mfma_i8(af[i][1], bf[j][0], I2[i][j]);
      }
    __builtin_amdgcn_s_setprio(0);
    __builtin_amdgcn_s_barrier();

    // ---- phase B: stage B(t+2); read A rows 2-3; MFMA half 1; counted vmcnt ----
    asm volatile("" ::: "memory");
    if (pf) stageB(sB2, t + 2);
#pragma unroll
    for (int i = 0; i < 2; ++i) {
      af[i][0] = rfi8(aS, 8192, 0, wm + (2 + i) * 16 + fr, fg);
      af[i][1] = rfi8(aS, 8192, 1, wm + (2 + i) * 16 + fr, fg);
    }
    __builtin_amdgcn_s_setprio(1);
#pragma unroll
    for (int i = 0; i < 2; ++i)
#pragma unroll
      for (int j = 0; j < 4; ++j) {
        I1[2 + i][j] = mfma_i8(af[i][0], bf[j][0], I1[2 + i][j]);
        I2[2 + i][j] = mfma_i8(af[i][0], bf[j][1], I2[2 + i][j]);
        I2[2 + i][j] = mfma_i8(af[i][1], bf[j][0], I2[2 + i][j]);
      }
    __builtin_amdgcn_s_setprio(0);
    if (pf) { asm volatile("s_waitcnt vmcnt(6)" ::: "memory"); }
    else    { asm volatile("s_waitcnt vmcnt(0)" ::: "memory"); }
    __builtin_amdgcn_s_barrier();
  }

  // ---- epilogue: dequant + bias + relu -> split-bf16 via LDS bounce ----
  short* ldsS = (short*)lds8;
  short* Oh = (short*)(ws + ohOff);
  short* Ol = (short*)(ws + olOff);
  const int fq4 = fg << 2;
#pragma unroll
  for (int rd = 0; rd < 2; ++rd) {
    __builtin_amdgcn_s_barrier();
#pragma unroll
    for (int i = 0; i < 4; ++i) {
      const int rl = wm + i * 16 + fq4;
      const f32x4 xs4 = *(const f32x4*)&XS[brow + rl];
#pragma unroll
      for (int j = 0; j < 4; ++j) {
        const int cl = wn + j * 16 + fr;
        const float wsc = __uint_as_float(WM[bcol + cl]) * (1.0f / 127.0f);
        const float bv = bias[bcol + cl];
#pragma unroll
        for (int e = 0; e < 4; ++e) {
          float u = ((float)I1[i][j][e] + (float)I2[i][j][e] * (1.0f / 256.0f)) *
                        (xs4[e] * wsc) + bv;
          u = fmaxf(u, 0.0f);
          short v;
          if (rd == 0) {
            v = f2bf(u);
          } else {
            const short hb = f2bf(u);
            v = f2bf(u - bf2f(hb));
          }
          ldsS[(rl + e) * 264 + cl] = v;
        }
      }
    }
    __builtin_amdgcn_s_barrier();
    short* gout = (rd == 0) ? Oh : Ol;
#pragma unroll
    for (int gi = 0; gi < 8; ++gi) {
      const int g = gi * 512 + tid;
      const int row = g >> 5, cg = g & 31;
      const short8 v = *(const short8*)&ldsS[row * 264 + cg * 8];
      *(short8*)&gout[(size_t)(brow + row) * N + bcol + cg * 8] = v;
    }
  }
}

// ---------------------------------------------------------------------------
// 256x256-tile 8-wave pipelined bf16 GEMM, 2 phases per K-tile (round-4 core).
// ---------------------------------------------------------------------------
constexpr int CH = 8192;        // shorts per 16KB chunk

template <int NAB>
DEV short8 read_frag(const short* base, int row, int s, int fg) {
  if constexpr (NAB == 1) {
    return *(const short8*)&base[row * 64 + ((((s << 2) | fg) ^ (row & 7)) << 3)];
  } else {
    return *(const short8*)&base[s * CH + row * 32 + ((fg ^ ((row >> 1) & 3)) << 3)];
  }
}

DEV f32x4 mfma16(short8 a, short8 b, f32x4 c) {
  return __builtin_amdgcn_mfma_f32_16x16x32_bf16(a, b, c, 0, 0, 0);
}

template <int NAB>
DEV void read_half(const short* aBase, int base_row, int fr, int fg, short8 (&av)[4][2]) {
#pragma unroll
  for (int i = 0; i < 4; ++i) {
    const int row = base_row + i * 16 + fr;
    av[i][0] = read_frag<NAB>(aBase, row, 0, fg);
    av[i][1] = read_frag<NAB>(aBase, row, 1, fg);
  }
}

template <int NAB, int H>
DEV void mfma_half(f32x4 (&acc)[8][4], const short8 (&av)[4][2], const short8 (&bfr)[4][2]) {
#pragma unroll
  for (int i = 0; i < 4; ++i)
#pragma unroll
    for (int j = 0; j < 4; ++j) {
      if constexpr (NAB == 1) {
        acc[H * 4 + i][j] = mfma16(av[i][0], bfr[j][0], acc[H * 4 + i][j]);
        acc[H * 4 + i][j] = mfma16(av[i][1], bfr[j][1], acc[H * 4 + i][j]);
      } else {
        acc[H * 4 + i][j] = mfma16(av[i][0], bfr[j][0], acc[H * 4 + i][j]);
        acc[H * 4 + i][j] = mfma16(av[i][0], bfr[j][1], acc[H * 4 + i][j]);
        acc[H * 4 + i][j] = mfma16(av[i][1], bfr[j][0], acc[H * 4 + i][j]);
      }
    }
}

template <int NAB, bool RELU, int STORE>
__launch_bounds__(512, 2)
__global__ void gemm8_k(unsigned char* wsb,
                        size_t aoff0, size_t aoff1, size_t boff0, size_t boff1,
                        const float* __restrict__ bias,
                        size_t ooff0, size_t ooff1, float* __restrict__ optr,
                        int M, int N, int K, int gx, int gxy) {
  constexpr int BK = (NAB == 2) ? 32 : 64;
  __shared__ alignas(16) short lds[10 * CH];

  unsigned char* ws = wsbase(wsb);
  const int tid = threadIdx.x;
  const int lane = tid & 63;
  const int wave = tid >> 6;
  const int wm = (wave >> 2) << 7;   // 0 / 128
  const int wn = (wave & 3) << 6;    // 0 / 64 / 128 / 192

  const int nwg = gridDim.x;
  const int q8 = nwg >> 3;
  const int id = (blockIdx.x & 7) * q8 + (blockIdx.x >> 3);
  const int bz = id / gxy;
  const int rem = id - bz * gxy;
  const int by = rem / gx;
  const int bx = rem - by * gx;
  const int brow = by << 8;
  const int bcol = bx << 8;

  const size_t batchA = (size_t)bz * M * K;
  const size_t batchB = (size_t)bz * N * K;
  const short* A0 = (const short*)(ws + aoff0) + batchA;
  const short* A1 = (const short*)(ws + aoff1) + batchA;
  const short* B0g = (const short*)(ws + boff0) + batchB;
  const short* B1g = (const short*)(ws + boff1) + batchB;

  size_t aSrc[2][2], bSrc[2][2];
#pragma unroll
  for (int h = 0; h < 2; ++h) {
    const int G = tid + h * 512;
    if constexpr (NAB == 1) {
      const int r = G >> 3, c = G & 7;
#pragma unroll
      for (int qq = 0; qq < 2; ++qq) {
        aSrc[qq][h] = (size_t)(brow + qq * 128 + r) * K + (size_t)((c ^ (r & 7)) << 3);
        bSrc[qq][h] = (size_t)(bcol + qq * 128 + r) * K + (size_t)((c ^ (r & 7)) << 3);
      }
    } else {
      const int r = G >> 2, c = G & 3;
      const size_t sw = (size_t)((c ^ ((r >> 1) & 3)) << 3);
      aSrc[0][h] = aSrc[1][h] = (size_t)(brow + r) * K + sw;
      bSrc[0][h] = bSrc[1][h] = (size_t)(bcol + r) * K + sw;
    }
  }
  const int ldst0 = tid << 3;

  auto issueA = [&](int slot, int qq, int tt) {
    short* dst = &lds[slot + qq * CH];
    const short* sp = (NAB == 2) ? (qq ? A1 : A0) : A0;
    const size_t ka = (size_t)tt * BK;
    gl16(sp + aSrc[qq][0] + ka, dst + ldst0);
    gl16(sp + aSrc[qq][1] + ka, dst + ldst0 + CH / 2);
  };
  auto issueB = [&](int slot, int qq, int tt) {
    short* dst = &lds[slot + qq * CH];
    const short* sp = (NAB == 2) ? (qq ? B1g : B0g) : B0g;
    const size_t ka = (size_t)tt * BK;
    gl16(sp + bSrc[qq][0] + ka, dst + ldst0);
    gl16(sp + bSrc[qq][1] + ka, dst + ldst0 + CH / 2);
  };

  const int nt = K / BK;
  const int fr = lane & 15;
  const int fg = lane >> 4;

  f32x4 acc[8][4] = {};

  issueA(0, 0, 0); issueA(0, 1, 0);
  issueB(6 * CH, 0, 0); issueB(6 * CH, 1, 0);
  if (nt > 1) {
    issueA(2 * CH, 0, 1); issueA(2 * CH, 1, 1);
    issueB(8 * CH, 0, 1); issueB(8 * CH, 1, 1);
    asm volatile("s_waitcnt vmcnt(8)" ::: "memory");
  } else {
    asm volatile("s_waitcnt vmcnt(0)" ::: "memory");
  }
  __builtin_amdgcn_s_barrier();

  for (int t = 0; t < nt; ++t) {
    const short* aBase = &lds[(t % 3) * (2 * CH)];
    const short* bBase = &lds[6 * CH + (t & 1) * (2 * CH)];
    const int sA2 = ((t + 2) % 3) * (2 * CH);
    const int sB  = 6 * CH + (t & 1) * (2 * CH);
    const bool pf = (t + 2 < nt);
    short8 bfr[4][2], av[4][2];

    if (pf) { issueA(sA2, 0, t + 2); issueA(sA2, 1, t + 2); }
#pragma unroll
    for (int j = 0; j < 4; ++j) {
      bfr[j][0] = read_frag<NAB>(bBase, wn + j * 16 + fr, 0, fg);
      bfr[j][1] = read_frag<NAB>(bBase, wn + j * 16 + fr, 1, fg);
    }
    read_half<NAB>(aBase, wm, fr, fg, av);
    __builtin_amdgcn_s_setprio(1);
    mfma_half<NAB, 0>(acc, av, bfr);
    __builtin_amdgcn_s_setprio(0);
    __builtin_amdgcn_s_barrier();

    asm volatile("" ::: "memory");
    if (pf) { issueB(sB, 0, t + 2); issueB(sB, 1, t + 2); }
    read_half<NAB>(aBase, wm + 64, fr, fg, av);
    __builtin_amdgcn_s_setprio(1);
    mfma_half<NAB, 1>(acc, av, bfr);
    __builtin_amdgcn_s_setprio(0);
    if (pf) {
      asm volatile("s_waitcnt vmcnt(8)" ::: "memory");
    } else {
      asm volatile("s_waitcnt vmcnt(0)" ::: "memory");
    }
    __builtin_amdgcn_s_barrier();
  }

  // ---- epilogue ----
  const int fq4 = (lane >> 4) << 2;
  if constexpr (STORE == 0 || STORE == 1) {
    short* Oh = (short*)(ws + ooff0);
    short* Ol = (short*)(ws + ooff1);
    constexpr int ROUNDS = (STORE == 0) ? 2 : 1;
#pragma unroll
    for (int rd = 0; rd < ROUNDS; ++rd) {
      __builtin_amdgcn_s_barrier();
#pragma unroll
      for (int i = 0; i < 8; ++i) {
        const int rl = wm + i * 16 + fq4;
#pragma unroll
        for (int j = 0; j < 4; ++j) {
          const int cl = wn + j * 16 + fr;
          const float bv = bias ? bias[bcol + cl] : 0.0f;
#pragma unroll
          for (int e = 0; e < 4; ++e) {
            float u = acc[i][j][e] + bv;
            if constexpr (RELU) u = fmaxf(u, 0.0f);
            short v;
            if (rd == 0) {
              v = f2bf(u);
            } else {
              const short hb = f2bf(u);
              v = f2bf(u - bf2f(hb));
            }
            lds[(rl + e) * 264 + cl] = v;
          }
        }
      }
      __builtin_amdgcn_s_barrier();
      short* gout = (rd == 0) ? Oh : Ol;
#pragma unroll
      for (int gi = 0; gi < 16; ++gi) {
        const int g = gi * 512 + tid;
        const int row = g >> 5, cg = g & 31;
        const short8 v = *(const short8*)&lds[row * 264 + cg * 8];
        *(short8*)&gout[(size_t)(brow + row) * N + bcol + cg * 8] = v;
      }
    }
  } else if constexpr (STORE == 2) {
    float* Of = (float*)(ws + ooff0) + (size_t)bz * M * N;
    float* ldsf = (float*)lds;
#pragma unroll
    for (int h = 0; h < 2; ++h) {
      __builtin_amdgcn_s_barrier();
      if ((wn & 128) == (h << 7)) {
#pragma unroll
        for (int i = 0; i < 8; ++i) {
          const int rl = wm + i * 16 + fq4;
#pragma unroll
          for (int j = 0; j < 4; ++j) {
            const int cp = (wn & 127) + j * 16 + fr;
#pragma unroll
            for (int e = 0; e < 4; ++e)
              ldsf[cp * 258 + rl + e] = acc[i][j][e];
          }
        }
      }
      __builtin_amdgcn_s_barrier();
#pragma unroll
      for (int gi = 0; gi < 16; ++gi) {
        const int g = gi * 512 + tid;
        const int tr = g >> 6, tc4 = (g & 63) << 2;
        const f32x4 v = *(const f32x4*)&ldsf[tr * 258 + tc4];
        *(f32x4*)&Of[(size_t)(bcol + h * 128 + tr) * M + brow + tc4] = v;
      }
    }
  } else {
    float* Op = optr + (size_t)bz * M * N;
    float* ldsf = (float*)lds;
#pragma unroll
    for (int h = 0; h < 2; ++h) {
      __builtin_amdgcn_s_barrier();
      if ((wm & 128) == (h << 7)) {
#pragma unroll
        for (int i = 0; i < 8; ++i) {
          const int rp = (wm & 127) + i * 16 + fq4;
#pragma unroll
          for (int j = 0; j < 4; ++j) {
            const int cl = wn + j * 16 + fr;
#pragma unroll
            for (int e = 0; e < 4; ++e)
              ldsf[(rp + e) * 258 + cl] = acc[i][j][e];
          }
        }
      }
      __builtin_amdgcn_s_barrier();
#pragma unroll
      for (int gi = 0; gi < 16; ++gi) {
        const int g = gi * 512 + tid;
        const int tr = g >> 6, tc4 = (g & 63) << 2;
        const f32x4 v = *(const f32x4*)&ldsf[tr * 258 + tc4];
        *(f32x4*)&Op[(size_t)(brow + h * 128 + tr) * N + bcol + tc4] = v;
      }
    }
  }
}

// ---------------------------------------------------------------------------
// row softmax over ST rows (axis-1 softmax of scores), output bf16 probs^T
// ---------------------------------------------------------------------------
__launch_bounds__(256)
__global__ void softmax_rows_k(unsigned char* wsb, size_t st, size_t pt) {
  constexpr int S = 2048;
  unsigned char* ws = wsbase(wsb);
  const f32x4* row = (const f32x4*)((const float*)(ws + st) + (size_t)blockIdx.x * S);
  short4v* out = (short4v*)((short*)(ws + pt) + (size_t)blockIdx.x * S);
  const int tid = threadIdx.x, lane = tid & 63, wv = tid >> 6;
  const f32x4 a = row[tid];
  const f32x4 b = row[tid + 256];
  float m = fmaxf(fmaxf(fmaxf(a[0], a[1]), fmaxf(a[2], a[3])),
                  fmaxf(fmaxf(b[0], b[1]), fmaxf(b[2], b[3])));
#pragma unroll
  for (int o = 32; o; o >>= 1) m = fmaxf(m, __shfl_xor(m, o));
  __shared__ float rb[8];
  if (lane == 0) rb[wv] = m;
  __syncthreads();
  m = fmaxf(fmaxf(rb[0], rb[1]), fmaxf(rb[2], rb[3]));
  float e[8];
  float s = 0.0f;
#pragma unroll
  for (int q = 0; q < 4; ++q) { e[q] = expf(a[q] - m); s += e[q]; }
#pragma unroll
  for (int q = 0; q < 4; ++q) { e[4 + q] = expf(b[q] - m); s += e[4 + q]; }
#pragma unroll
  for (int o = 32; o; o >>= 1) s += __shfl_xor(s, o);
  if (lane == 0) rb[4 + wv] = s;
  __syncthreads();
  s = rb[4] + rb[5] + rb[6] + rb[7];
  const float inv = 1.0f / s;
  short4v o1, o2;
#pragma unroll
  for (int q = 0; q < 4; ++q) { o1[q] = f2bf(e[q] * inv); o2[q] = f2bf(e[4 + q] * inv); }
  out[tid] = o1;
  out[tid + 256] = o2;
}

// ---------------------------------------------------------------------------
extern "C" void kernel_launch(void* const* d_in, const int* in_sizes, int n_in,
                              void* d_out, int out_size, void* d_ws, size_t ws_size,
                              hipStream_t stream) {
  const float* x   = (const float*)d_in[0];
  const float* qw1 = (const float*)d_in[1];
  const float* qb1 = (const float*)d_in[2];
  const float* qw2 = (const float*)d_in[3];
  const float* qb2 = (const float*)d_in[4];
  const float* kw1 = (const float*)d_in[5];
  const float* kb1 = (const float*)d_in[6];
  const float* kw2 = (const float*)d_in[7];
  const float* kb2 = (const float*)d_in[8];
  const float* vw1 = (const float*)d_in[9];
  const float* vb1 = (const float*)d_in[10];
  const float* vw2 = (const float*)d_in[11];
  const float* vb2 = (const float*)d_in[12];
  float* out = (float*)d_out;
  unsigned char* wsb = (ws_size >= WS_TOTAL) ? (unsigned char*)d_ws : nullptr;
  unsigned char* wsr;
  if (wsb) wsr = wsb;
  else { hipError_t e = hipGetSymbolAddress((void**)&wsr, HIP_SYMBOL(g_ws)); (void)e; }

  const int M = BB * SS;  // 8192
  dim3 blk(512);
  dim3 tb(32, 8);

  // zero the per-column weight-max arrays (atomicMax targets)
  hipMemsetAsync(wsr + OFF_WMQ, 0, 32768, stream);
  hipMemsetAsync(wsr + OFF_WMK, 0, 32768, stream);

  // x -> i8 2-level (for Q/K MLP1) and bf16 hi (for V MLP1)
  quant_x_k<<<8192, 256, 0, stream>>>(x, wsb, OFF_XA1, OFF_XA2, OFF_XS);
  cast_hi_k<<<4096, 256, 0, stream>>>(x, wsb, OFF_XH, NX / 4);

  // ---- Q path: MLP1 in i8, MLP2 in split-bf16 ----
  colmax_k<<<dim3(HHID / 256, DD / 128), 256, 0, stream>>>(qw1, wsb, OFF_WMQ, DD, HHID);
  transpose_quant_k<<<dim3(HHID / 32, DD / 32), tb, 0, stream>>>(qw1, wsb, OFF_WA1, OFF_WA2, OFF_WMQ, DD, HHID);
  gemm_i8_k<<<2048, blk, 0, stream>>>(wsb, OFF_XA1, OFF_XA2, OFF_WA1, OFF_WA2,
                                      OFF_XS, OFF_WMQ, qb1, OFF_HH, OFF_HL,
                                      M, HHID, DD, 32, 2048);
  transpose_cast_k<<<dim3(DD / 32, HHID / 32), tb, 0, stream>>>(qw2, wsb, OFF_WH, OFF_WL, HHID, DD, 1);
  gemm8_k<2, false, 0><<<256, blk, 0, stream>>>(
      wsb, OFF_HH, OFF_HL, OFF_WH, OFF_WL, qb2, OFF_QH, OFF_QL, nullptr, M, DD, HHID, 8, 256);

  // ---- K path ----
  colmax_k<<<dim3(HHID / 256, DD / 128), 256, 0, stream>>>(kw1, wsb, OFF_WMK, DD, HHID);
  transpose_quant_k<<<dim3(HHID / 32, DD / 32), tb, 0, stream>>>(kw1, wsb, OFF_WA1, OFF_WA2, OFF_WMK, DD, HHID);
  gemm_i8_k<<<2048, blk, 0, stream>>>(wsb, OFF_XA1, OFF_XA2, OFF_WA1, OFF_WA2,
                                      OFF_XS, OFF_WMK, kb1, OFF_HH, OFF_HL,
                                      M, HHID, DD, 32, 2048);
  transpose_cast_k<<<dim3(DD / 32, HHID / 32), tb, 0, stream>>>(kw2, wsb, OFF_WH, OFF_WL, HHID, DD, 1);
  gemm8_k<2, false, 0><<<256, blk, 0, stream>>>(
      wsb, OFF_HH, OFF_HL, OFF_WH, OFF_WL, kb2, OFF_KH, OFF_KL, nullptr, M, DD, HHID, 8, 256);

  // ---- V path (plain bf16) ----
  transpose_cast_k<<<dim3(HHID / 32, DD / 32), tb, 0, stream>>>(vw1, wsb, OFF_WH, OFF_WL, DD, HHID, 0);
  gemm8_k<1, true, 1><<<1024, blk, 0, stream>>>(
      wsb, OFF_XH, 0, OFF_WH, 0, vb1, OFF_HH, 0, nullptr, M, HHID, DD, 32, 1024);
  transpose_cast_k<<<dim3(DD / 32, HHID / 32), tb, 0, stream>>>(vw2, wsb, OFF_WH, OFF_WL, HHID, DD, 0);
  gemm8_k<1, false, 1><<<256, blk, 0, stream>>>(
      wsb, OFF_HH, 0, OFF_WH, 0, vb2, OFF_V, 0, nullptr, M, DD, HHID, 8, 256);

  // ---- scores^T = (Q K^T)^T per batch, split precision, fp32 ----
  gemm8_k<2, false, 2><<<256, blk, 0, stream>>>(
      wsb, OFF_QH, OFF_QL, OFF_KH, OFF_KL, nullptr, OFF_ST, 0, nullptr, SS, SS, DD, 8, 64);

  // ---- softmax over axis 1 == row softmax of ST; writes bf16 probs^T ----
  softmax_rows_k<<<BB * SS, 256, 0, stream>>>(wsb, OFF_ST, OFF_PT);

  // ---- out = V @ probs  (B^T = probs^T), fp32 to d_out ----
  gemm8_k<1, false, 3><<<256, blk, 0, stream>>>(
      wsb, OFF_V, 0, OFF_PT, 0, nullptr, 0, 0, out, SS, SS, DD, 8, 64);
}

// Round 7
// 2789.943 us; speedup vs baseline: 1.4020x; 1.0989x over previous
//
#include <hip/hip_runtime.h>
#include <cstdint>
#include <cstddef>

typedef __attribute__((ext_vector_type(8))) short short8;
typedef __attribute__((ext_vector_type(4))) short short4v;
typedef __attribute__((ext_vector_type(4))) float f32x4;
typedef __attribute__((ext_vector_type(4))) int i32x4;

#define DEV __device__ __forceinline__

// Problem geometry (fixed by the reference)
constexpr int DD = 2048;           // D
constexpr int HHID = 8192;         // H
constexpr int BB = 4;              // B
constexpr int SS = 2048;           // S
constexpr size_t NX = (size_t)BB * SS * DD;   // 16,777,216
constexpr size_t NW = (size_t)DD * HHID;      // 16,777,216
constexpr size_t NH = (size_t)BB * SS * HHID; // 67,108,864

// Scratch layout (bytes)
constexpr size_t OFF_XH  = 0;                    // x bf16 hi (V path)
constexpr size_t OFF_XA1 = OFF_XH + NX * 2;      // x i8 lvl1
constexpr size_t OFF_XA2 = OFF_XA1 + NX;         // x i8 lvl2
constexpr size_t OFF_WA1 = OFF_XA2 + NX;         // weight i8 lvl1 (reused 4x)
constexpr size_t OFF_WA2 = OFF_WA1 + NW;         // weight i8 lvl2
constexpr size_t OFF_WHV = OFF_WA1;              // alias: V-path bf16 weights (NW*2)
constexpr size_t OFF_HH  = OFF_WA2 + NW;         // h bf16 hi / hV bf16 / ST alias
constexpr size_t OFF_HL  = OFF_HH + NH * 2;      // h bf16 lo / PT alias
constexpr size_t OFF_QKH = OFF_HL + NH * 2;      // Q-then-K split hi (reused)
constexpr size_t OFF_QKL = OFF_QKH + NX * 2;
constexpr size_t OFF_QA1 = OFF_QKL + NX * 2;     // Q i8
constexpr size_t OFF_QA2 = OFF_QA1 + NX;
constexpr size_t OFF_KA1 = OFF_QA2 + NX;         // K i8
constexpr size_t OFF_KA2 = OFF_KA1 + NX;
constexpr size_t OFF_HA1 = OFF_KA2 + NX;         // h i8 (reused Q/K paths)
constexpr size_t OFF_HA2 = OFF_HA1 + NH;
constexpr size_t OFF_V   = OFF_HA2 + NH;         // V bf16
constexpr size_t OFF_XS  = OFF_V + NX * 2;       // f32[8192] x row scales
constexpr size_t OFF_HS  = OFF_XS + 32768;       // f32[8192] h row scales
constexpr size_t OFF_QS  = OFF_HS + 32768;       // f32[8192] Q row scales
constexpr size_t OFF_KS  = OFF_QS + 32768;       // f32[8192] K row scales
constexpr size_t OFF_CM  = OFF_KS + 32768;       // colmax scratch (reused 4x)
constexpr size_t WS_TOTAL = OFF_CM + 32768;
constexpr size_t OFF_ST = OFF_HH;                // fp32 scores^T
constexpr size_t OFF_PT = OFF_HL;                // bf16 probs^T

__device__ __align__(256) unsigned char g_ws[WS_TOTAL];

DEV unsigned char* wsbase(unsigned char* p) { return p ? p : (unsigned char*)g_ws; }
DEV short f2bf(float v) { __bf16 b = (__bf16)v; return __builtin_bit_cast(short, b); }
DEV float bf2f(short s) { return (float)__builtin_bit_cast(__bf16, s); }

DEV void gl16(const short* g, short* l) {
  __builtin_amdgcn_global_load_lds((const __attribute__((address_space(1))) void*)g,
                                   (__attribute__((address_space(3))) void*)l, 16, 0, 0);
}
DEV void gl16b(const signed char* g, signed char* l) {
  __builtin_amdgcn_global_load_lds((const __attribute__((address_space(1))) void*)g,
                                   (__attribute__((address_space(3))) void*)l, 16, 0, 0);
}

// ---------------------------------------------------------------------------
// cast x -> bf16 hi (V path)
// ---------------------------------------------------------------------------
__global__ void cast_hi_k(const float* __restrict__ x, unsigned char* wsb,
                          size_t oh, size_t n4) {
  unsigned char* ws = wsbase(wsb);
  short4v* OH = (short4v*)(ws + oh);
  const f32x4* X = (const f32x4*)x;
  for (size_t i = (size_t)blockIdx.x * blockDim.x + threadIdx.x; i < n4;
       i += (size_t)gridDim.x * blockDim.x) {
    const f32x4 v = X[i];
    short4v hs;
#pragma unroll
    for (int e = 0; e < 4; ++e) hs[e] = f2bf(v[e]);
    OH[i] = hs;
  }
}

// ---------------------------------------------------------------------------
// per-row 2-level i8 quantization of fp32 x (rowlen 2048)
// ---------------------------------------------------------------------------
__launch_bounds__(256)
__global__ void quant_x_k(const float* __restrict__ x, unsigned char* wsb,
                          size_t oa1, size_t oa2, size_t oxs) {
  unsigned char* ws = wsbase(wsb);
  signed char* A1 = (signed char*)(ws + oa1);
  signed char* A2 = (signed char*)(ws + oa2);
  float* XS = (float*)(ws + oxs);
  const int row = blockIdx.x;
  const float* xr = x + (size_t)row * 2048;
  const int tid = threadIdx.x, lane = tid & 63;
  const f32x4 v0 = *(const f32x4*)&xr[tid * 8];
  const f32x4 v1 = *(const f32x4*)&xr[tid * 8 + 4];
  float m = 0.0f;
#pragma unroll
  for (int e = 0; e < 4; ++e) m = fmaxf(m, fmaxf(fabsf(v0[e]), fabsf(v1[e])));
#pragma unroll
  for (int o = 32; o; o >>= 1) m = fmaxf(m, __shfl_xor(m, o));
  __shared__ float rb[4];
  if (lane == 0) rb[tid >> 6] = m;
  __syncthreads();
  m = fmaxf(fmaxf(rb[0], rb[1]), fmaxf(rb[2], rb[3]));
  const float inv = (m > 1e-30f) ? 127.0f / m : 0.0f;
  if (tid == 0) XS[row] = m * (1.0f / 127.0f);
  unsigned int w1a = 0, w1b = 0, w2a = 0, w2b = 0;
#pragma unroll
  for (int e = 0; e < 8; ++e) {
    const float xv = (e < 4) ? v0[e] : v1[e - 4];
    const float q = xv * inv;
    const float a1f = rintf(q);
    int ia2 = (int)rintf((q - a1f) * 256.0f);
    ia2 = ia2 > 127 ? 127 : (ia2 < -127 ? -127 : ia2);
    const unsigned int b1 = (unsigned char)(signed char)(int)a1f;
    const unsigned int b2 = (unsigned char)(signed char)ia2;
    if (e < 4) { w1a |= b1 << (8 * e); w2a |= b2 << (8 * e); }
    else       { w1b |= b1 << (8 * (e - 4)); w2b |= b2 << (8 * (e - 4)); }
  }
  const size_t o = (size_t)row * 2048 + tid * 8;
  *(unsigned int*)&A1[o] = w1a; *(unsigned int*)&A1[o + 4] = w1b;
  *(unsigned int*)&A2[o] = w2a; *(unsigned int*)&A2[o + 4] = w2b;
}

// ---------------------------------------------------------------------------
// per-row 2-level i8 quantization of split-bf16 (hi+lo) matrix rows
// block = rowlen/8 threads (<=1024); grid = nrows
// ---------------------------------------------------------------------------
__launch_bounds__(1024)
__global__ void rowquant_k(unsigned char* wsb, size_t hho, size_t hlo,
                           size_t oa1, size_t oa2, size_t oso, int rowlen) {
  unsigned char* ws = wsbase(wsb);
  const int row = blockIdx.x, tid = threadIdx.x, lane = tid & 63, wv = tid >> 6;
  const int nw = blockDim.x >> 6;
  const short8 hi = *((const short8*)((const short*)(ws + hho) + (size_t)row * rowlen) + tid);
  const short8 lo = *((const short8*)((const short*)(ws + hlo) + (size_t)row * rowlen) + tid);
  float v[8]; float m = 0.0f;
#pragma unroll
  for (int e = 0; e < 8; ++e) {
    v[e] = bf2f(hi[e]) + bf2f(lo[e]);
    m = fmaxf(m, fabsf(v[e]));
  }
#pragma unroll
  for (int o = 32; o; o >>= 1) m = fmaxf(m, __shfl_xor(m, o));
  __shared__ float rb[16];
  if (lane == 0) rb[wv] = m;
  __syncthreads();
  m = rb[0];
  for (int i = 1; i < nw; ++i) m = fmaxf(m, rb[i]);
  const float inv = (m > 1e-30f) ? 127.0f / m : 0.0f;
  if (tid == 0) ((float*)(ws + oso))[row] = m * (1.0f / 127.0f);
  unsigned int w1a = 0, w1b = 0, w2a = 0, w2b = 0;
#pragma unroll
  for (int e = 0; e < 8; ++e) {
    const float q = v[e] * inv;
    const float a1f = rintf(q);
    int ia2 = (int)rintf((q - a1f) * 256.0f);
    ia2 = ia2 > 127 ? 127 : (ia2 < -127 ? -127 : ia2);
    const unsigned int b1 = (unsigned char)(signed char)(int)a1f;
    const unsigned int b2 = (unsigned char)(signed char)ia2;
    if (e < 4) { w1a |= b1 << (8 * e); w2a |= b2 << (8 * e); }
    else       { w1b |= b1 << (8 * (e - 4)); w2b |= b2 << (8 * (e - 4)); }
  }
  const size_t o = (size_t)row * rowlen + tid * 8;
  signed char* A1 = (signed char*)(ws + oa1);
  signed char* A2 = (signed char*)(ws + oa2);
  *(unsigned int*)&A1[o] = w1a; *(unsigned int*)&A1[o + 4] = w1b;
  *(unsigned int*)&A2[o] = w2a; *(unsigned int*)&A2[o + 4] = w2b;
}

// ---------------------------------------------------------------------------
// per-column absmax of w [R][C] -> MX[col] (uint-encoded float, memset to 0)
// ---------------------------------------------------------------------------
__launch_bounds__(256)
__global__ void colmax_k(const float* __restrict__ w, unsigned char* wsb,
                         size_t omax, int R, int C) {
  unsigned char* ws = wsbase(wsb);
  unsigned int* MX = (unsigned int*)(ws + omax);
  const int col = blockIdx.x * 256 + threadIdx.x;
  const int r0 = blockIdx.y * 128;
  float m = 0.0f;
  for (int r = 0; r < 128; ++r) m = fmaxf(m, fabsf(w[(size_t)(r0 + r) * C + col]));
  atomicMax(&MX[col], __float_as_uint(m));
}

// in-place: uint-encoded absmax -> f32 scale (max/127)
__global__ void scalefix_k(unsigned char* wsb, size_t off, int n) {
  unsigned char* ws = wsbase(wsb);
  const int i = blockIdx.x * 256 + threadIdx.x;
  if (i < n) {
    float* p = (float*)(ws + off);
    const unsigned int u = ((const unsigned int*)p)[i];
    p[i] = __uint_as_float(u) * (1.0f / 127.0f);
  }
}

// ---------------------------------------------------------------------------
// transpose + 2-level i8 quant: src R x C fp32 -> a1,a2 [C][R] i8 (f32 col scale)
// ---------------------------------------------------------------------------
__global__ void transpose_quant_k(const float* __restrict__ src, unsigned char* wsb,
                                  size_t oa1, size_t oa2, size_t osc, int R, int C) {
  __shared__ float t[32][33];
  unsigned char* ws = wsbase(wsb);
  signed char* A1 = (signed char*)(ws + oa1);
  signed char* A2 = (signed char*)(ws + oa2);
  const float* SC = (const float*)(ws + osc);
  const int c0 = blockIdx.x << 5, r0 = blockIdx.y << 5;
  const int x = threadIdx.x, y = threadIdx.y;
#pragma unroll
  for (int i = 0; i < 4; ++i) {
    const int rr = y + (i << 3);
    t[rr][x] = src[(size_t)(r0 + rr) * C + c0 + x];
  }
  __syncthreads();
#pragma unroll
  for (int i = 0; i < 4; ++i) {
    const int oc = y + (i << 3);
    const float v = t[x][oc];
    const float s = SC[c0 + oc];
    const float inv = (s > 1e-38f) ? 1.0f / s : 0.0f;
    const float q = v * inv;
    const float a1f = rintf(q);
    int ia2 = (int)rintf((q - a1f) * 256.0f);
    ia2 = ia2 > 127 ? 127 : (ia2 < -127 ? -127 : ia2);
    const size_t o = (size_t)(c0 + oc) * R + r0 + x;
    A1[o] = (signed char)(int)a1f;
    A2[o] = (signed char)ia2;
  }
}

// ---------------------------------------------------------------------------
// transpose + cast: src R x C fp32 -> out C x R bf16 hi (V path weights)
// ---------------------------------------------------------------------------
__global__ void transpose_cast_k(const float* __restrict__ src, unsigned char* wsb,
                                 size_t oh, int R, int C) {
  __shared__ float t[32][33];
  unsigned char* ws = wsbase(wsb);
  short* OH = (short*)(ws + oh);
  const int c0 = blockIdx.x << 5, r0 = blockIdx.y << 5;
  const int x = threadIdx.x, y = threadIdx.y;
#pragma unroll
  for (int i = 0; i < 4; ++i) {
    const int rr = y + (i << 3);
    t[rr][x] = src[(size_t)(r0 + rr) * C + c0 + x];
  }
  __syncthreads();
#pragma unroll
  for (int i = 0; i < 4; ++i) {
    const int oc = y + (i << 3);
    OH[(size_t)(c0 + oc) * R + r0 + x] = f2bf(t[x][oc]);
  }
}

// ---------------------------------------------------------------------------
// 2-level i8 GEMM: C[m][n] ~ sa[m]*sb[n]*(I1 + I2/256)  (+bias, +relu)
// 16x16x64 i8 MFMA, 3 terms. Tile 128x256, 8 waves, BK=64; A 3-slot/B 2-slot
// LDS (112KB), 2-phase schedule, counted vmcnt(6). Batched via gxy.
// STORE: 0 = (+bias/relu) split-bf16 out [row][N]; 2 = fp32 transposed ST[n][m].
// ---------------------------------------------------------------------------
DEV i32x4 mfma_i8(i32x4 a, i32x4 b, i32x4 c) {
  return __builtin_amdgcn_mfma_i32_16x16x64_i8(a, b, c, 0, 0, 0);
}
DEV i32x4 rfi8(const signed char* base, int lstride, int L, int row, int fg) {
  return *(const i32x4*)&base[L * lstride + row * 64 + ((fg ^ ((row >> 1) & 3)) << 4)];
}

template <bool RELU, int STORE>
__launch_bounds__(512, 2)
__global__ void gemm_i8_k(unsigned char* wsb,
                          size_t a1o, size_t a2o, size_t b1o, size_t b2o,
                          size_t aso, size_t bso, const float* __restrict__ bias,
                          size_t o0, size_t o1, int M, int N, int K,
                          int gx, int gxy) {
  __shared__ alignas(16) signed char lds8[114688];

  unsigned char* ws = wsbase(wsb);
  const int tid = threadIdx.x;
  const int lane = tid & 63;
  const int wave = tid >> 6;
  const int wm = (wave >> 2) << 6;   // 0 / 64
  const int wn = (wave & 3) << 6;    // 0 / 64 / 128 / 192
  const int fr = lane & 15;
  const int fg = lane >> 4;

  // bijective XCD swizzle (nwg multiple of 8)
  const int nwg = gridDim.x;
  const int q8 = nwg >> 3;
  const int id = (blockIdx.x & 7) * q8 + (blockIdx.x >> 3);
  const int bz = id / gxy;
  const int rem = id - bz * gxy;
  const int by = rem / gx;
  const int bx = rem - by * gx;
  const int brow = by << 7;    // 128-row tiles
  const int bcol = bx << 8;    // 256-col tiles

  const size_t batchA = (size_t)bz * M * K;
  const size_t batchB = (STORE == 2) ? (size_t)bz * N * K : 0;
  const signed char* Xa1 = (const signed char*)(ws + a1o) + batchA;
  const signed char* Xa2 = (const signed char*)(ws + a2o) + batchA;
  const signed char* Wa1 = (const signed char*)(ws + b1o) + batchB;
  const signed char* Wa2 = (const signed char*)(ws + b2o) + batchB;
  const float* AS = (const float*)(ws + aso) + (size_t)bz * M;
  const float* BS = (const float*)(ws + bso) + ((STORE == 2) ? (size_t)bz * N : 0);

  // staging source offsets (granule-swizzled, granule = 16 i8)
  const int ar = tid >> 2, ac = tid & 3;
  const size_t aOff = (size_t)(brow + ar) * K + ((ac ^ ((ar >> 1) & 3)) << 4);
  size_t bOff[2];
#pragma unroll
  for (int h = 0; h < 2; ++h) {
    const int G = tid + h * 512;
    const int r = G >> 2, c = G & 3;
    bOff[h] = (size_t)(bcol + r) * K + ((c ^ ((r >> 1) & 3)) << 4);
  }

  auto stageA = [&](int slotBase, int tt) {   // 2 gl16
    const int ko = tt * 64;
    gl16b(Xa1 + aOff + ko, &lds8[slotBase + (tid << 4)]);
    gl16b(Xa2 + aOff + ko, &lds8[slotBase + 8192 + (tid << 4)]);
  };
  auto stageB = [&](int slotBase, int tt) {   // 4 gl16
    const int ko = tt * 64;
#pragma unroll
    for (int h = 0; h < 2; ++h) {
      gl16b(Wa1 + bOff[h] + ko, &lds8[slotBase + ((tid + h * 512) << 4)]);
      gl16b(Wa2 + bOff[h] + ko, &lds8[slotBase + 16384 + ((tid + h * 512) << 4)]);
    }
  };

  const int nt = K / 64;
  i32x4 I1[4][4] = {};
  i32x4 I2[4][4] = {};

  // prologue: A0,B0,A1,B1
  stageA(0, 0);
  stageB(49152, 0);
  if (nt > 1) { stageA(16384, 1); stageB(49152 + 32768, 1); }
  if (nt > 1) { asm volatile("s_waitcnt vmcnt(6)" ::: "memory"); }
  else        { asm volatile("s_waitcnt vmcnt(0)" ::: "memory"); }
  __builtin_amdgcn_s_barrier();

  for (int t = 0; t < nt; ++t) {
    const signed char* aS = &lds8[(t % 3) * 16384];
    const signed char* bS = &lds8[49152 + (t & 1) * 32768];
    const int sA2 = ((t + 2) % 3) * 16384;
    const int sB2 = 49152 + (t & 1) * 32768;
    const bool pf = (t + 2 < nt);
    i32x4 bf[4][2], af[2][2];

    // ---- phase A: stage A(t+2); read all B frags + A rows 0-1; MFMA half 0 ----
    if (pf) stageA(sA2, t + 2);
#pragma unroll
    for (int j = 0; j < 4; ++j) {
      bf[j][0] = rfi8(bS, 16384, 0, wn + j * 16 + fr, fg);
      bf[j][1] = rfi8(bS, 16384, 1, wn + j * 16 + fr, fg);
    }
#pragma unroll
    for (int i = 0; i < 2; ++i) {
      af[i][0] = rfi8(aS, 8192, 0, wm + i * 16 + fr, fg);
      af[i][1] = rfi8(aS, 8192, 1, wm + i * 16 + fr, fg);
    }
    __builtin_amdgcn_s_setprio(1);
#pragma unroll
    for (int i = 0; i < 2; ++i)
#pragma unroll
      for (int j = 0; j < 4; ++j) {
        I1[i][j] = mfma_i8(af[i][0], bf[j][0], I1[i][j]);
        I2[i][j] = mfma_i8(af[i][0], bf[j][1], I2[i][j]);
        I2[i][j] = mfma_i8(af[i][1], bf[j][0], I2[i][j]);
      }
    __builtin_amdgcn_s_setprio(0);
    __builtin_amdgcn_s_barrier();

    // ---- phase B: stage B(t+2); read A rows 2-3; MFMA half 1; counted vmcnt ----
    asm volatile("" ::: "memory");
    if (pf) stageB(sB2, t + 2);
#pragma unroll
    for (int i = 0; i < 2; ++i) {
      af[i][0] = rfi8(aS, 8192, 0, wm + (2 + i) * 16 + fr, fg);
      af[i][1] = rfi8(aS, 8192, 1, wm + (2 + i) * 16 + fr, fg);
    }
    __builtin_amdgcn_s_setprio(1);
#pragma unroll
    for (int i = 0; i < 2; ++i)
#pragma unroll
      for (int j = 0; j < 4; ++j) {
        I1[2 + i][j] = mfma_i8(af[i][0], bf[j][0], I1[2 + i][j]);
        I2[2 + i][j] = mfma_i8(af[i][0], bf[j][1], I2[2 + i][j]);
        I2[2 + i][j] = mfma_i8(af[i][1], bf[j][0], I2[2 + i][j]);
      }
    __builtin_amdgcn_s_setprio(0);
    if (pf) { asm volatile("s_waitcnt vmcnt(6)" ::: "memory"); }
    else    { asm volatile("s_waitcnt vmcnt(0)" ::: "memory"); }
    __builtin_amdgcn_s_barrier();
  }

  const int fq4 = fg << 2;
  if constexpr (STORE == 0) {
    // ---- dequant + bias (+relu) -> split-bf16 via LDS bounce ----
    short* ldsS = (short*)lds8;
    short* Oh = (short*)(ws + o0);
    short* Ol = (short*)(ws + o1);
#pragma unroll
    for (int rd = 0; rd < 2; ++rd) {
      __builtin_amdgcn_s_barrier();
#pragma unroll
      for (int i = 0; i < 4; ++i) {
        const int rl = wm + i * 16 + fq4;
        const f32x4 sa4 = *(const f32x4*)&AS[brow + rl];
#pragma unroll
        for (int j = 0; j < 4; ++j) {
          const int cl = wn + j * 16 + fr;
          const float sb = BS[bcol + cl];
          const float bv = bias ? bias[bcol + cl] : 0.0f;
#pragma unroll
          for (int e = 0; e < 4; ++e) {
            float u = ((float)I1[i][j][e] + (float)I2[i][j][e] * (1.0f / 256.0f)) *
                          (sa4[e] * sb) + bv;
            if (RELU) u = fmaxf(u, 0.0f);
            short v;
            if (rd == 0) {
              v = f2bf(u);
            } else {
              const short hb = f2bf(u);
              v = f2bf(u - bf2f(hb));
            }
            ldsS[(rl + e) * 264 + cl] = v;
          }
        }
      }
      __builtin_amdgcn_s_barrier();
      short* gout = (rd == 0) ? Oh : Ol;
#pragma unroll
      for (int gi = 0; gi < 8; ++gi) {
        const int g = gi * 512 + tid;
        const int row = g >> 5, cg = g & 31;
        const short8 v = *(const short8*)&ldsS[row * 264 + cg * 8];
        *(short8*)&gout[(size_t)(brow + row) * N + bcol + cg * 8] = v;
      }
    }
  } else {
    // ---- dequant -> fp32 TRANSPOSED ST[n][m] via LDS bounce (batched) ----
    float* Of = (float*)(ws + o0) + (size_t)bz * M * N;
    float* ldsf = (float*)lds8;
#pragma unroll
    for (int h2 = 0; h2 < 2; ++h2) {
      __builtin_amdgcn_s_barrier();
      if ((wn >> 7) == h2) {
#pragma unroll
        for (int i = 0; i < 4; ++i) {
          const int rl = wm + i * 16 + fq4;
          const f32x4 sa4 = *(const f32x4*)&AS[brow + rl];
#pragma unroll
          for (int j = 0; j < 4; ++j) {
            const int cp = (wn & 127) + j * 16 + fr;
            const float sb = BS[bcol + wn + j * 16 + fr];
            f32x4 u;
#pragma unroll
            for (int e = 0; e < 4; ++e)
              u[e] = ((float)I1[i][j][e] + (float)I2[i][j][e] * (1.0f / 256.0f)) *
                     (sa4[e] * sb);
            *(f32x4*)&ldsf[cp * 132 + rl] = u;
          }
        }
      }
      __builtin_amdgcn_s_barrier();
#pragma unroll
      for (int gi = 0; gi < 8; ++gi) {
        const int g = gi * 512 + tid;
        const int tr = g >> 5, tc4 = (g & 31) << 2;
        const f32x4 v = *(const f32x4*)&ldsf[tr * 132 + tc4];
        *(f32x4*)&Of[(size_t)(bcol + h2 * 128 + tr) * M + brow + tc4] = v;
      }
    }
  }
}

// ---------------------------------------------------------------------------
// 256x256-tile 8-wave pipelined bf16 GEMM, 2 phases per K-tile (round-4 core).
// NAB=1 plain bf16, BK=64. STORE: 1 bf16 out, 3 fp32 optr bounce.
// ---------------------------------------------------------------------------
constexpr int CH = 8192;        // shorts per 16KB chunk

DEV short8 read_frag1(const short* base, int row, int s, int fg) {
  return *(const short8*)&base[row * 64 + ((((s << 2) | fg) ^ (row & 7)) << 3)];
}

DEV f32x4 mfma16(short8 a, short8 b, f32x4 c) {
  return __builtin_amdgcn_mfma_f32_16x16x32_bf16(a, b, c, 0, 0, 0);
}

template <bool RELU, int STORE>
__launch_bounds__(512, 2)
__global__ void gemm8_k(unsigned char* wsb,
                        size_t aoff0, size_t boff0,
                        const float* __restrict__ bias,
                        size_t ooff0, float* __restrict__ optr,
                        int M, int N, int K, int gx, int gxy) {
  __shared__ alignas(16) short lds[10 * CH];

  unsigned char* ws = wsbase(wsb);
  const int tid = threadIdx.x;
  const int lane = tid & 63;
  const int wave = tid >> 6;
  const int wm = (wave >> 2) << 7;   // 0 / 128
  const int wn = (wave & 3) << 6;    // 0 / 64 / 128 / 192

  const int nwg = gridDim.x;
  const int q8 = nwg >> 3;
  const int id = (blockIdx.x & 7) * q8 + (blockIdx.x >> 3);
  const int bz = id / gxy;
  const int rem = id - bz * gxy;
  const int by = rem / gx;
  const int bx = rem - by * gx;
  const int brow = by << 8;
  const int bcol = bx << 8;

  const short* A0 = (const short*)(ws + aoff0) + (size_t)bz * M * K;
  const short* B0g = (const short*)(ws + boff0) + (size_t)bz * N * K;

  size_t aSrc[2][2], bSrc[2][2];
#pragma unroll
  for (int h = 0; h < 2; ++h) {
    const int G = tid + h * 512;
    const int r = G >> 3, c = G & 7;
#pragma unroll
    for (int qq = 0; qq < 2; ++qq) {
      aSrc[qq][h] = (size_t)(brow + qq * 128 + r) * K + (size_t)((c ^ (r & 7)) << 3);
      bSrc[qq][h] = (size_t)(bcol + qq * 128 + r) * K + (size_t)((c ^ (r & 7)) << 3);
    }
  }
  const int ldst0 = tid << 3;

  auto issueA = [&](int slot, int qq, int tt) {
    short* dst = &lds[slot + qq * CH];
    const size_t ka = (size_t)tt * 64;
    gl16(A0 + aSrc[qq][0] + ka, dst + ldst0);
    gl16(A0 + aSrc[qq][1] + ka, dst + ldst0 + CH / 2);
  };
  auto issueB = [&](int slot, int qq, int tt) {
    short* dst = &lds[slot + qq * CH];
    const size_t ka = (size_t)tt * 64;
    gl16(B0g + bSrc[qq][0] + ka, dst + ldst0);
    gl16(B0g + bSrc[qq][1] + ka, dst + ldst0 + CH / 2);
  };

  const int nt = K / 64;
  const int fr = lane & 15;
  const int fg = lane >> 4;

  f32x4 acc[8][4] = {};

  issueA(0, 0, 0); issueA(0, 1, 0);
  issueB(6 * CH, 0, 0); issueB(6 * CH, 1, 0);
  if (nt > 1) {
    issueA(2 * CH, 0, 1); issueA(2 * CH, 1, 1);
    issueB(8 * CH, 0, 1); issueB(8 * CH, 1, 1);
    asm volatile("s_waitcnt vmcnt(8)" ::: "memory");
  } else {
    asm volatile("s_waitcnt vmcnt(0)" ::: "memory");
  }
  __builtin_amdgcn_s_barrier();

  for (int t = 0; t < nt; ++t) {
    const short* aBase = &lds[(t % 3) * (2 * CH)];
    const short* bBase = &lds[6 * CH + (t & 1) * (2 * CH)];
    const int sA2 = ((t + 2) % 3) * (2 * CH);
    const int sB  = 6 * CH + (t & 1) * (2 * CH);
    const bool pf = (t + 2 < nt);
    short8 bfr[4][2], av[4][2];

    if (pf) { issueA(sA2, 0, t + 2); issueA(sA2, 1, t + 2); }
#pragma unroll
    for (int j = 0; j < 4; ++j) {
      bfr[j][0] = read_frag1(bBase, wn + j * 16 + fr, 0, fg);
      bfr[j][1] = read_frag1(bBase, wn + j * 16 + fr, 1, fg);
    }
#pragma unroll
    for (int i = 0; i < 4; ++i) {
      av[i][0] = read_frag1(aBase, wm + i * 16 + fr, 0, fg);
      av[i][1] = read_frag1(aBase, wm + i * 16 + fr, 1, fg);
    }
    __builtin_amdgcn_s_setprio(1);
#pragma unroll
    for (int i = 0; i < 4; ++i)
#pragma unroll
      for (int j = 0; j < 4; ++j) {
        acc[i][j] = mfma16(av[i][0], bfr[j][0], acc[i][j]);
        acc[i][j] = mfma16(av[i][1], bfr[j][1], acc[i][j]);
      }
    __builtin_amdgcn_s_setprio(0);
    __builtin_amdgcn_s_barrier();

    asm volatile("" ::: "memory");
    if (pf) { issueB(sB, 0, t + 2); issueB(sB, 1, t + 2); }
#pragma unroll
    for (int i = 0; i < 4; ++i) {
      av[i][0] = read_frag1(aBase, wm + 64 + i * 16 + fr, 0, fg);
      av[i][1] = read_frag1(aBase, wm + 64 + i * 16 + fr, 1, fg);
    }
    __builtin_amdgcn_s_setprio(1);
#pragma unroll
    for (int i = 0; i < 4; ++i)
#pragma unroll
      for (int j = 0; j < 4; ++j) {
        acc[4 + i][j] = mfma16(av[i][0], bfr[j][0], acc[4 + i][j]);
        acc[4 + i][j] = mfma16(av[i][1], bfr[j][1], acc[4 + i][j]);
      }
    __builtin_amdgcn_s_setprio(0);
    if (pf) {
      asm volatile("s_waitcnt vmcnt(8)" ::: "memory");
    } else {
      asm volatile("s_waitcnt vmcnt(0)" ::: "memory");
    }
    __builtin_amdgcn_s_barrier();
  }

  // ---- epilogue ----
  const int fq4 = (lane >> 4) << 2;
  if constexpr (STORE == 1) {
    short* Oh = (short*)(ws + ooff0);
    __builtin_amdgcn_s_barrier();
#pragma unroll
    for (int i = 0; i < 8; ++i) {
      const int rl = wm + i * 16 + fq4;
#pragma unroll
      for (int j = 0; j < 4; ++j) {
        const int cl = wn + j * 16 + fr;
        const float bv = bias ? bias[bcol + cl] : 0.0f;
#pragma unroll
        for (int e = 0; e < 4; ++e) {
          float u = acc[i][j][e] + bv;
          if (RELU) u = fmaxf(u, 0.0f);
          lds[(rl + e) * 264 + cl] = f2bf(u);
        }
      }
    }
    __builtin_amdgcn_s_barrier();
#pragma unroll
    for (int gi = 0; gi < 16; ++gi) {
      const int g = gi * 512 + tid;
      const int row = g >> 5, cg = g & 31;
      const short8 v = *(const short8*)&lds[row * 264 + cg * 8];
      *(short8*)&Oh[(size_t)(brow + row) * N + bcol + cg * 8] = v;
    }
  } else {
    float* Op = optr + (size_t)bz * M * N;
    float* ldsf = (float*)lds;
#pragma unroll
    for (int h = 0; h < 2; ++h) {
      __builtin_amdgcn_s_barrier();
      if ((wm & 128) == (h << 7)) {
#pragma unroll
        for (int i = 0; i < 8; ++i) {
          const int rp = (wm & 127) + i * 16 + fq4;
#pragma unroll
          for (int j = 0; j < 4; ++j) {
            const int cl = wn + j * 16 + fr;
#pragma unroll
            for (int e = 0; e < 4; ++e)
              ldsf[(rp + e) * 258 + cl] = acc[i][j][e];
          }
        }
      }
      __builtin_amdgcn_s_barrier();
#pragma unroll
      for (int gi = 0; gi < 16; ++gi) {
        const int g = gi * 512 + tid;
        const int tr = g >> 6, tc4 = (g & 63) << 2;
        const f32x4 v = *(const f32x4*)&ldsf[tr * 258 + tc4];
        *(f32x4*)&Op[(size_t)(brow + h * 128 + tr) * N + bcol + tc4] = v;
      }
    }
  }
}

// ---------------------------------------------------------------------------
// row softmax over ST rows (axis-1 softmax of scores), output bf16 probs^T
// ---------------------------------------------------------------------------
__launch_bounds__(256)
__global__ void softmax_rows_k(unsigned char* wsb, size_t st, size_t pt) {
  constexpr int S = 2048;
  unsigned char* ws = wsbase(wsb);
  const f32x4* row = (const f32x4*)((const float*)(ws + st) + (size_t)blockIdx.x * S);
  short4v* out = (short4v*)((short*)(ws + pt) + (size_t)blockIdx.x * S);
  const int tid = threadIdx.x, lane = tid & 63, wv = tid >> 6;
  const f32x4 a = row[tid];
  const f32x4 b = row[tid + 256];
  float m = fmaxf(fmaxf(fmaxf(a[0], a[1]), fmaxf(a[2], a[3])),
                  fmaxf(fmaxf(b[0], b[1]), fmaxf(b[2], b[3])));
#pragma unroll
  for (int o = 32; o; o >>= 1) m = fmaxf(m, __shfl_xor(m, o));
  __shared__ float rb[8];
  if (lane == 0) rb[wv] = m;
  __syncthreads();
  m = fmaxf(fmaxf(rb[0], rb[1]), fmaxf(rb[2], rb[3]));
  float e[8];
  float s = 0.0f;
#pragma unroll
  for (int q = 0; q < 4; ++q) { e[q] = expf(a[q] - m); s += e[q]; }
#pragma unroll
  for (int q = 0; q < 4; ++q) { e[4 + q] = expf(b[q] - m); s += e[4 + q]; }
#pragma unroll
  for (int o = 32; o; o >>= 1) s += __shfl_xor(s, o);
  if (lane == 0) rb[4 + wv] = s;
  __syncthreads();
  s = rb[4] + rb[5] + rb[6] + rb[7];
  const float inv = 1.0f / s;
  short4v o1, o2;
#pragma unroll
  for (int q = 0; q < 4; ++q) { o1[q] = f2bf(e[q] * inv); o2[q] = f2bf(e[4 + q] * inv); }
  out[tid] = o1;
  out[tid + 256] = o2;
}

// ---------------------------------------------------------------------------
extern "C" void kernel_launch(void* const* d_in, const int* in_sizes, int n_in,
                              void* d_out, int out_size, void* d_ws, size_t ws_size,
                              hipStream_t stream) {
  const float* x   = (const float*)d_in[0];
  const float* qw1 = (const float*)d_in[1];
  const float* qb1 = (const float*)d_in[2];
  const float* qw2 = (const float*)d_in[3];
  const float* qb2 = (const float*)d_in[4];
  const float* kw1 = (const float*)d_in[5];
  const float* kb1 = (const float*)d_in[6];
  const float* kw2 = (const float*)d_in[7];
  const float* kb2 = (const float*)d_in[8];
  const float* vw1 = (const float*)d_in[9];
  const float* vb1 = (const float*)d_in[10];
  const float* vw2 = (const float*)d_in[11];
  const float* vb2 = (const float*)d_in[12];
  float* out = (float*)d_out;
  unsigned char* wsb = (ws_size >= WS_TOTAL) ? (unsigned char*)d_ws : nullptr;
  unsigned char* wsr;
  if (wsb) wsr = wsb;
  else { hipError_t e = hipGetSymbolAddress((void**)&wsr, HIP_SYMBOL(g_ws)); (void)e; }

  const int M = BB * SS;  // 8192
  dim3 blk(512);
  dim3 tb(32, 8);

  // x -> i8 2-level (Q/K MLP1) and bf16 hi (V MLP1)
  quant_x_k<<<8192, 256, 0, stream>>>(x, wsb, OFF_XA1, OFF_XA2, OFF_XS);
  cast_hi_k<<<4096, 256, 0, stream>>>(x, wsb, OFF_XH, NX / 4);

  // ================= Q path (all i8) =================
  hipMemsetAsync(wsr + OFF_CM, 0, 32768, stream);
  colmax_k<<<dim3(HHID / 256, DD / 128), 256, 0, stream>>>(qw1, wsb, OFF_CM, DD, HHID);
  scalefix_k<<<32, 256, 0, stream>>>(wsb, OFF_CM, HHID);
  transpose_quant_k<<<dim3(HHID / 32, DD / 32), tb, 0, stream>>>(qw1, wsb, OFF_WA1, OFF_WA2, OFF_CM, DD, HHID);
  gemm_i8_k<true, 0><<<2048, blk, 0, stream>>>(wsb, OFF_XA1, OFF_XA2, OFF_WA1, OFF_WA2,
                                               OFF_XS, OFF_CM, qb1, OFF_HH, OFF_HL,
                                               M, HHID, DD, 32, 2048);
  rowquant_k<<<8192, 1024, 0, stream>>>(wsb, OFF_HH, OFF_HL, OFF_HA1, OFF_HA2, OFF_HS, HHID);
  hipMemsetAsync(wsr + OFF_CM, 0, 32768, stream);
  colmax_k<<<dim3(DD / 256, HHID / 128), 256, 0, stream>>>(qw2, wsb, OFF_CM, HHID, DD);
  scalefix_k<<<8, 256, 0, stream>>>(wsb, OFF_CM, DD);
  transpose_quant_k<<<dim3(DD / 32, HHID / 32), tb, 0, stream>>>(qw2, wsb, OFF_WA1, OFF_WA2, OFF_CM, HHID, DD);
  gemm_i8_k<false, 0><<<512, blk, 0, stream>>>(wsb, OFF_HA1, OFF_HA2, OFF_WA1, OFF_WA2,
                                               OFF_HS, OFF_CM, qb2, OFF_QKH, OFF_QKL,
                                               M, DD, HHID, 8, 512);
  rowquant_k<<<8192, 256, 0, stream>>>(wsb, OFF_QKH, OFF_QKL, OFF_QA1, OFF_QA2, OFF_QS, DD);

  // ================= K path (all i8) =================
  hipMemsetAsync(wsr + OFF_CM, 0, 32768, stream);
  colmax_k<<<dim3(HHID / 256, DD / 128), 256, 0, stream>>>(kw1, wsb, OFF_CM, DD, HHID);
  scalefix_k<<<32, 256, 0, stream>>>(wsb, OFF_CM, HHID);
  transpose_quant_k<<<dim3(HHID / 32, DD / 32), tb, 0, stream>>>(kw1, wsb, OFF_WA1, OFF_WA2, OFF_CM, DD, HHID);
  gemm_i8_k<true, 0><<<2048, blk, 0, stream>>>(wsb, OFF_XA1, OFF_XA2, OFF_WA1, OFF_WA2,
                                               OFF_XS, OFF_CM, kb1, OFF_HH, OFF_HL,
                                               M, HHID, DD, 32, 2048);
  rowquant_k<<<8192, 1024, 0, stream>>>(wsb, OFF_HH, OFF_HL, OFF_HA1, OFF_HA2, OFF_HS, HHID);
  hipMemsetAsync(wsr + OFF_CM, 0, 32768, stream);
  colmax_k<<<dim3(DD / 256, HHID / 128), 256, 0, stream>>>(kw2, wsb, OFF_CM, HHID, DD);
  scalefix_k<<<8, 256, 0, stream>>>(wsb, OFF_CM, DD);
  transpose_quant_k<<<dim3(DD / 32, HHID / 32), tb, 0, stream>>>(kw2, wsb, OFF_WA1, OFF_WA2, OFF_CM, HHID, DD);
  gemm_i8_k<false, 0><<<512, blk, 0, stream>>>(wsb, OFF_HA1, OFF_HA2, OFF_WA1, OFF_WA2,
                                               OFF_HS, OFF_CM, kb2, OFF_QKH, OFF_QKL,
                                               M, DD, HHID, 8, 512);
  rowquant_k<<<8192, 256, 0, stream>>>(wsb, OFF_QKH, OFF_QKL, OFF_KA1, OFF_KA2, OFF_KS, DD);

  // ================= V path (plain bf16) =================
  transpose_cast_k<<<dim3(HHID / 32, DD / 32), tb, 0, stream>>>(vw1, wsb, OFF_WHV, DD, HHID);
  gemm8_k<true, 1><<<1024, blk, 0, stream>>>(
      wsb, OFF_XH, OFF_WHV, vb1, OFF_HH, nullptr, M, HHID, DD, 32, 1024);
  transpose_cast_k<<<dim3(DD / 32, HHID / 32), tb, 0, stream>>>(vw2, wsb, OFF_WHV, HHID, DD);
  gemm8_k<false, 1><<<256, blk, 0, stream>>>(
      wsb, OFF_HH, OFF_WHV, vb2, OFF_V, nullptr, M, DD, HHID, 8, 256);

  // ---- scores^T (i8, batched): ST[t][s] per batch ----
  gemm_i8_k<false, 2><<<512, blk, 0, stream>>>(wsb, OFF_QA1, OFF_QA2, OFF_KA1, OFF_KA2,
                                               OFF_QS, OFF_KS, nullptr, OFF_ST, 0,
                                               SS, SS, DD, 8, 128);

  // ---- softmax over axis 1 == row softmax of ST; writes bf16 probs^T ----
  softmax_rows_k<<<BB * SS, 256, 0, stream>>>(wsb, OFF_ST, OFF_PT);

  // ---- out = V @ probs  (B^T = probs^T), fp32 to d_out ----
  gemm8_k<false, 3><<<256, blk, 0, stream>>>(
      wsb, OFF_V, OFF_PT, nullptr, 0, out, SS, SS, DD, 8, 64);
}

// Round 8
// 2735.995 us; speedup vs baseline: 1.4296x; 1.0197x over previous
//
#include <hip/hip_runtime.h>
#include <cstdint>
#include <cstddef>

typedef __attribute__((ext_vector_type(8))) short short8;
typedef __attribute__((ext_vector_type(4))) short short4v;
typedef __attribute__((ext_vector_type(4))) float f32x4;
typedef __attribute__((ext_vector_type(4))) int i32x4;

#define DEV __device__ __forceinline__

// Problem geometry (fixed by the reference)
constexpr int DD = 2048;           // D
constexpr int HHID = 8192;         // H
constexpr int BB = 4;              // B
constexpr int SS = 2048;           // S
constexpr size_t NX = (size_t)BB * SS * DD;   // 16,777,216
constexpr size_t NW = (size_t)DD * HHID;      // 16,777,216
constexpr size_t NH = (size_t)BB * SS * HHID; // 67,108,864

// Scratch layout (bytes)
constexpr size_t OFF_XH  = 0;                    // x bf16 hi (V path)
constexpr size_t OFF_XA1 = OFF_XH + NX * 2;      // x i8 lvl1
constexpr size_t OFF_XA2 = OFF_XA1 + NX;         // x i8 lvl2
constexpr size_t OFF_WA1 = OFF_XA2 + NX;         // weight i8 lvl1 (reused 4x)
constexpr size_t OFF_WA2 = OFF_WA1 + NW;         // weight i8 lvl2
constexpr size_t OFF_WHV = OFF_WA1;              // alias: V-path bf16 weights (NW*2)
constexpr size_t OFF_HH  = OFF_WA2 + NW;         // h bf16 hi / hV bf16 / ST alias
constexpr size_t OFF_HL  = OFF_HH + NH * 2;      // h bf16 lo / PT alias
constexpr size_t OFF_QKH = OFF_HL + NH * 2;      // Q-then-K split hi (reused)
constexpr size_t OFF_QKL = OFF_QKH + NX * 2;
constexpr size_t OFF_QA1 = OFF_QKL + NX * 2;     // Q i8
constexpr size_t OFF_QA2 = OFF_QA1 + NX;
constexpr size_t OFF_KA1 = OFF_QA2 + NX;         // K i8
constexpr size_t OFF_KA2 = OFF_KA1 + NX;
constexpr size_t OFF_HA1 = OFF_KA2 + NX;         // h i8 (reused Q/K paths)
constexpr size_t OFF_HA2 = OFF_HA1 + NH;
constexpr size_t OFF_V   = OFF_HA2 + NH;         // V bf16
constexpr size_t OFF_XS  = OFF_V + NX * 2;       // f32[8192] x row scales
constexpr size_t OFF_HS  = OFF_XS + 32768;       // f32[8192] h row scales
constexpr size_t OFF_QS  = OFF_HS + 32768;       // f32[8192] Q row scales
constexpr size_t OFF_KS  = OFF_QS + 32768;       // f32[8192] K row scales
constexpr size_t OFF_CM  = OFF_KS + 32768;       // colmax scratch (reused 4x)
constexpr size_t WS_TOTAL = OFF_CM + 32768;
constexpr size_t OFF_ST = OFF_HH;                // fp32 scores^T
constexpr size_t OFF_PT = OFF_HL;                // bf16 probs^T

__device__ __align__(256) unsigned char g_ws[WS_TOTAL];

DEV unsigned char* wsbase(unsigned char* p) { return p ? p : (unsigned char*)g_ws; }
DEV short f2bf(float v) { __bf16 b = (__bf16)v; return __builtin_bit_cast(short, b); }
DEV float bf2f(short s) { return (float)__builtin_bit_cast(__bf16, s); }

template <typename T> DEV void nts(T v, T* p) { __builtin_nontemporal_store(v, p); }
template <typename T> DEV T ntl(const T* p) { return __builtin_nontemporal_load(p); }

DEV void gl16(const short* g, short* l) {
  __builtin_amdgcn_global_load_lds((const __attribute__((address_space(1))) void*)g,
                                   (__attribute__((address_space(3))) void*)l, 16, 0, 0);
}
DEV void gl16b(const signed char* g, signed char* l) {
  __builtin_amdgcn_global_load_lds((const __attribute__((address_space(1))) void*)g,
                                   (__attribute__((address_space(3))) void*)l, 16, 0, 0);
}

// ---------------------------------------------------------------------------
// cast x -> bf16 hi (V path). x already cached by quant_x_k -> nt read.
// ---------------------------------------------------------------------------
__global__ void cast_hi_k(const float* __restrict__ x, unsigned char* wsb,
                          size_t oh, size_t n4) {
  unsigned char* ws = wsbase(wsb);
  short4v* OH = (short4v*)(ws + oh);
  const f32x4* X = (const f32x4*)x;
  for (size_t i = (size_t)blockIdx.x * blockDim.x + threadIdx.x; i < n4;
       i += (size_t)gridDim.x * blockDim.x) {
    const f32x4 v = ntl(&X[i]);
    short4v hs;
#pragma unroll
    for (int e = 0; e < 4; ++e) hs[e] = f2bf(v[e]);
    OH[i] = hs;
  }
}

// ---------------------------------------------------------------------------
// per-row 2-level i8 quantization of fp32 x (rowlen 2048)
// ---------------------------------------------------------------------------
__launch_bounds__(256)
__global__ void quant_x_k(const float* __restrict__ x, unsigned char* wsb,
                          size_t oa1, size_t oa2, size_t oxs) {
  unsigned char* ws = wsbase(wsb);
  signed char* A1 = (signed char*)(ws + oa1);
  signed char* A2 = (signed char*)(ws + oa2);
  float* XS = (float*)(ws + oxs);
  const int row = blockIdx.x;
  const float* xr = x + (size_t)row * 2048;
  const int tid = threadIdx.x, lane = tid & 63;
  const f32x4 v0 = *(const f32x4*)&xr[tid * 8];
  const f32x4 v1 = *(const f32x4*)&xr[tid * 8 + 4];
  float m = 0.0f;
#pragma unroll
  for (int e = 0; e < 4; ++e) m = fmaxf(m, fmaxf(fabsf(v0[e]), fabsf(v1[e])));
#pragma unroll
  for (int o = 32; o; o >>= 1) m = fmaxf(m, __shfl_xor(m, o));
  __shared__ float rb[4];
  if (lane == 0) rb[tid >> 6] = m;
  __syncthreads();
  m = fmaxf(fmaxf(rb[0], rb[1]), fmaxf(rb[2], rb[3]));
  const float inv = (m > 1e-30f) ? 127.0f / m : 0.0f;
  if (tid == 0) XS[row] = m * (1.0f / 127.0f);
  unsigned int w1a = 0, w1b = 0, w2a = 0, w2b = 0;
#pragma unroll
  for (int e = 0; e < 8; ++e) {
    const float xv = (e < 4) ? v0[e] : v1[e - 4];
    const float q = xv * inv;
    const float a1f = rintf(q);
    int ia2 = (int)rintf((q - a1f) * 256.0f);
    ia2 = ia2 > 127 ? 127 : (ia2 < -127 ? -127 : ia2);
    const unsigned int b1 = (unsigned char)(signed char)(int)a1f;
    const unsigned int b2 = (unsigned char)(signed char)ia2;
    if (e < 4) { w1a |= b1 << (8 * e); w2a |= b2 << (8 * e); }
    else       { w1b |= b1 << (8 * (e - 4)); w2b |= b2 << (8 * (e - 4)); }
  }
  const size_t o = (size_t)row * 2048 + tid * 8;
  *(unsigned int*)&A1[o] = w1a; *(unsigned int*)&A1[o + 4] = w1b;
  *(unsigned int*)&A2[o] = w2a; *(unsigned int*)&A2[o + 4] = w2b;
}

// ---------------------------------------------------------------------------
// per-row 2-level i8 quantization of split-bf16 (hi+lo) matrix rows.
// hi/lo are read-once streams -> nontemporal loads.
// ---------------------------------------------------------------------------
__launch_bounds__(1024)
__global__ void rowquant_k(unsigned char* wsb, size_t hho, size_t hlo,
                           size_t oa1, size_t oa2, size_t oso, int rowlen) {
  unsigned char* ws = wsbase(wsb);
  const int row = blockIdx.x, tid = threadIdx.x, lane = tid & 63, wv = tid >> 6;
  const int nw = blockDim.x >> 6;
  const short8 hi = ntl((const short8*)((const short*)(ws + hho) + (size_t)row * rowlen) + tid);
  const short8 lo = ntl((const short8*)((const short*)(ws + hlo) + (size_t)row * rowlen) + tid);
  float v[8]; float m = 0.0f;
#pragma unroll
  for (int e = 0; e < 8; ++e) {
    v[e] = bf2f(hi[e]) + bf2f(lo[e]);
    m = fmaxf(m, fabsf(v[e]));
  }
#pragma unroll
  for (int o = 32; o; o >>= 1) m = fmaxf(m, __shfl_xor(m, o));
  __shared__ float rb[16];
  if (lane == 0) rb[wv] = m;
  __syncthreads();
  m = rb[0];
  for (int i = 1; i < nw; ++i) m = fmaxf(m, rb[i]);
  const float inv = (m > 1e-30f) ? 127.0f / m : 0.0f;
  if (tid == 0) ((float*)(ws + oso))[row] = m * (1.0f / 127.0f);
  unsigned int w1a = 0, w1b = 0, w2a = 0, w2b = 0;
#pragma unroll
  for (int e = 0; e < 8; ++e) {
    const float q = v[e] * inv;
    const float a1f = rintf(q);
    int ia2 = (int)rintf((q - a1f) * 256.0f);
    ia2 = ia2 > 127 ? 127 : (ia2 < -127 ? -127 : ia2);
    const unsigned int b1 = (unsigned char)(signed char)(int)a1f;
    const unsigned int b2 = (unsigned char)(signed char)ia2;
    if (e < 4) { w1a |= b1 << (8 * e); w2a |= b2 << (8 * e); }
    else       { w1b |= b1 << (8 * (e - 4)); w2b |= b2 << (8 * (e - 4)); }
  }
  const size_t o = (size_t)row * rowlen + tid * 8;
  signed char* A1 = (signed char*)(ws + oa1);
  signed char* A2 = (signed char*)(ws + oa2);
  *(unsigned int*)&A1[o] = w1a; *(unsigned int*)&A1[o + 4] = w1b;
  *(unsigned int*)&A2[o] = w2a; *(unsigned int*)&A2[o + 4] = w2b;
}

// ---------------------------------------------------------------------------
// per-column absmax of w [R][C] -> MX[col] (uint-encoded float, memset to 0)
// first reader of w: normal (cached) reads so transpose_quant hits L3
// ---------------------------------------------------------------------------
__launch_bounds__(256)
__global__ void colmax_k(const float* __restrict__ w, unsigned char* wsb,
                         size_t omax, int R, int C) {
  unsigned char* ws = wsbase(wsb);
  unsigned int* MX = (unsigned int*)(ws + omax);
  const int col = blockIdx.x * 256 + threadIdx.x;
  const int r0 = blockIdx.y * 128;
  float m = 0.0f;
  for (int r = 0; r < 128; ++r) m = fmaxf(m, fabsf(w[(size_t)(r0 + r) * C + col]));
  atomicMax(&MX[col], __float_as_uint(m));
}

// in-place: uint-encoded absmax -> f32 scale (max/127)
__global__ void scalefix_k(unsigned char* wsb, size_t off, int n) {
  unsigned char* ws = wsbase(wsb);
  const int i = blockIdx.x * 256 + threadIdx.x;
  if (i < n) {
    float* p = (float*)(ws + off);
    const unsigned int u = ((const unsigned int*)p)[i];
    p[i] = __uint_as_float(u) * (1.0f / 127.0f);
  }
}

// ---------------------------------------------------------------------------
// transpose + 2-level i8 quant: src R x C fp32 -> a1,a2 [C][R] i8 (f32 col scale)
// src is last-use -> nt loads
// ---------------------------------------------------------------------------
__global__ void transpose_quant_k(const float* __restrict__ src, unsigned char* wsb,
                                  size_t oa1, size_t oa2, size_t osc, int R, int C) {
  __shared__ float t[32][33];
  unsigned char* ws = wsbase(wsb);
  signed char* A1 = (signed char*)(ws + oa1);
  signed char* A2 = (signed char*)(ws + oa2);
  const float* SC = (const float*)(ws + osc);
  const int c0 = blockIdx.x << 5, r0 = blockIdx.y << 5;
  const int x = threadIdx.x, y = threadIdx.y;
#pragma unroll
  for (int i = 0; i < 4; ++i) {
    const int rr = y + (i << 3);
    t[rr][x] = ntl(&src[(size_t)(r0 + rr) * C + c0 + x]);
  }
  __syncthreads();
#pragma unroll
  for (int i = 0; i < 4; ++i) {
    const int oc = y + (i << 3);
    const float v = t[x][oc];
    const float s = SC[c0 + oc];
    const float inv = (s > 1e-38f) ? 1.0f / s : 0.0f;
    const float q = v * inv;
    const float a1f = rintf(q);
    int ia2 = (int)rintf((q - a1f) * 256.0f);
    ia2 = ia2 > 127 ? 127 : (ia2 < -127 ? -127 : ia2);
    const size_t o = (size_t)(c0 + oc) * R + r0 + x;
    A1[o] = (signed char)(int)a1f;
    A2[o] = (signed char)ia2;
  }
}

// ---------------------------------------------------------------------------
// transpose + cast: src R x C fp32 -> out C x R bf16 hi (V path weights)
// ---------------------------------------------------------------------------
__global__ void transpose_cast_k(const float* __restrict__ src, unsigned char* wsb,
                                 size_t oh, int R, int C) {
  __shared__ float t[32][33];
  unsigned char* ws = wsbase(wsb);
  short* OH = (short*)(ws + oh);
  const int c0 = blockIdx.x << 5, r0 = blockIdx.y << 5;
  const int x = threadIdx.x, y = threadIdx.y;
#pragma unroll
  for (int i = 0; i < 4; ++i) {
    const int rr = y + (i << 3);
    t[rr][x] = ntl(&src[(size_t)(r0 + rr) * C + c0 + x]);
  }
  __syncthreads();
#pragma unroll
  for (int i = 0; i < 4; ++i) {
    const int oc = y + (i << 3);
    OH[(size_t)(c0 + oc) * R + r0 + x] = f2bf(t[x][oc]);
  }
}

// ---------------------------------------------------------------------------
// 2-level i8 GEMM: C[m][n] ~ sa[m]*sb[n]*(I1 + I2/256)  (+bias, +relu)
// 16x16x64 i8 MFMA, 3 terms. Tile 128x256, 8 waves, BK=64; A 3-slot/B 2-slot
// LDS (112KB), 2-phase schedule, counted vmcnt(6). Batched via gxy.
// STORE: 0 = (+bias/relu) split-bf16 out [row][N]; 2 = fp32 transposed ST[n][m].
// All epilogue stores are NONTEMPORAL (streaming outputs; protect L3 operand
// residency -> avoids the 16x HBM read amplification measured in round 7).
// ---------------------------------------------------------------------------
DEV i32x4 mfma_i8(i32x4 a, i32x4 b, i32x4 c) {
  return __builtin_amdgcn_mfma_i32_16x16x64_i8(a, b, c, 0, 0, 0);
}
DEV i32x4 rfi8(const signed char* base, int lstride, int L, int row, int fg) {
  return *(const i32x4*)&base[L * lstride + row * 64 + ((fg ^ ((row >> 1) & 3)) << 4)];
}

template <bool RELU, int STORE>
__launch_bounds__(512, 2)
__global__ void gemm_i8_k(unsigned char* wsb,
                          size_t a1o, size_t a2o, size_t b1o, size_t b2o,
                          size_t aso, size_t bso, const float* __restrict__ bias,
                          size_t o0, size_t o1, int M, int N, int K,
                          int gx, int gxy) {
  __shared__ alignas(16) signed char lds8[114688];

  unsigned char* ws = wsbase(wsb);
  const int tid = threadIdx.x;
  const int lane = tid & 63;
  const int wave = tid >> 6;
  const int wm = (wave >> 2) << 6;   // 0 / 64
  const int wn = (wave & 3) << 6;    // 0 / 64 / 128 / 192
  const int fr = lane & 15;
  const int fg = lane >> 4;

  // bijective XCD swizzle (nwg multiple of 8)
  const int nwg = gridDim.x;
  const int q8 = nwg >> 3;
  const int id = (blockIdx.x & 7) * q8 + (blockIdx.x >> 3);
  const int bz = id / gxy;
  const int rem = id - bz * gxy;
  const int by = rem / gx;
  const int bx = rem - by * gx;
  const int brow = by << 7;    // 128-row tiles
  const int bcol = bx << 8;    // 256-col tiles

  const size_t batchA = (size_t)bz * M * K;
  const size_t batchB = (STORE == 2) ? (size_t)bz * N * K : 0;
  const signed char* Xa1 = (const signed char*)(ws + a1o) + batchA;
  const signed char* Xa2 = (const signed char*)(ws + a2o) + batchA;
  const signed char* Wa1 = (const signed char*)(ws + b1o) + batchB;
  const signed char* Wa2 = (const signed char*)(ws + b2o) + batchB;
  const float* AS = (const float*)(ws + aso) + (size_t)bz * M;
  const float* BS = (const float*)(ws + bso) + ((STORE == 2) ? (size_t)bz * N : 0);

  // staging source offsets (granule-swizzled, granule = 16 i8)
  const int ar = tid >> 2, ac = tid & 3;
  const size_t aOff = (size_t)(brow + ar) * K + ((ac ^ ((ar >> 1) & 3)) << 4);
  size_t bOff[2];
#pragma unroll
  for (int h = 0; h < 2; ++h) {
    const int G = tid + h * 512;
    const int r = G >> 2, c = G & 3;
    bOff[h] = (size_t)(bcol + r) * K + ((c ^ ((r >> 1) & 3)) << 4);
  }

  auto stageA = [&](int slotBase, int tt) {   // 2 gl16
    const int ko = tt * 64;
    gl16b(Xa1 + aOff + ko, &lds8[slotBase + (tid << 4)]);
    gl16b(Xa2 + aOff + ko, &lds8[slotBase + 8192 + (tid << 4)]);
  };
  auto stageB = [&](int slotBase, int tt) {   // 4 gl16
    const int ko = tt * 64;
#pragma unroll
    for (int h = 0; h < 2; ++h) {
      gl16b(Wa1 + bOff[h] + ko, &lds8[slotBase + ((tid + h * 512) << 4)]);
      gl16b(Wa2 + bOff[h] + ko, &lds8[slotBase + 16384 + ((tid + h * 512) << 4)]);
    }
  };

  const int nt = K / 64;
  i32x4 I1[4][4] = {};
  i32x4 I2[4][4] = {};

  // prologue: A0,B0,A1,B1
  stageA(0, 0);
  stageB(49152, 0);
  if (nt > 1) { stageA(16384, 1); stageB(49152 + 32768, 1); }
  if (nt > 1) { asm volatile("s_waitcnt vmcnt(6)" ::: "memory"); }
  else        { asm volatile("s_waitcnt vmcnt(0)" ::: "memory"); }
  __builtin_amdgcn_s_barrier();

  for (int t = 0; t < nt; ++t) {
    const signed char* aS = &lds8[(t % 3) * 16384];
    const signed char* bS = &lds8[49152 + (t & 1) * 32768];
    const int sA2 = ((t + 2) % 3) * 16384;
    const int sB2 = 49152 + (t & 1) * 32768;
    const bool pf = (t + 2 < nt);
    i32x4 bf[4][2], af[2][2];

    // ---- phase A: stage A(t+2); read all B frags + A rows 0-1; MFMA half 0 ----
    if (pf) stageA(sA2, t + 2);
#pragma unroll
    for (int j = 0; j < 4; ++j) {
      bf[j][0] = rfi8(bS, 16384, 0, wn + j * 16 + fr, fg);
      bf[j][1] = rfi8(bS, 16384, 1, wn + j * 16 + fr, fg);
    }
#pragma unroll
    for (int i = 0; i < 2; ++i) {
      af[i][0] = rfi8(aS, 8192, 0, wm + i * 16 + fr, fg);
      af[i][1] = rfi8(aS, 8192, 1, wm + i * 16 + fr, fg);
    }
    __builtin_amdgcn_s_setprio(1);
#pragma unroll
    for (int i = 0; i < 2; ++i)
#pragma unroll
      for (int j = 0; j < 4; ++j) {
        I1[i][j] = mfma_i8(af[i][0], bf[j][0], I1[i][j]);
        I2[i][j] = mfma_i8(af[i][0], bf[j][1], I2[i][j]);
        I2[i][j] = mfma_i8(af[i][1], bf[j][0], I2[i][j]);
      }
    __builtin_amdgcn_s_setprio(0);
    __builtin_amdgcn_s_barrier();

    // ---- phase B: stage B(t+2); read A rows 2-3; MFMA half 1; counted vmcnt ----
    asm volatile("" ::: "memory");
    if (pf) stageB(sB2, t + 2);
#pragma unroll
    for (int i = 0; i < 2; ++i) {
      af[i][0] = rfi8(aS, 8192, 0, wm + (2 + i) * 16 + fr, fg);
      af[i][1] = rfi8(aS, 8192, 1, wm + (2 + i) * 16 + fr, fg);
    }
    __builtin_amdgcn_s_setprio(1);
#pragma unroll
    for (int i = 0; i < 2; ++i)
#pragma unroll
      for (int j = 0; j < 4; ++j) {
        I1[2 + i][j] = mfma_i8(af[i][0], bf[j][0], I1[2 + i][j]);
        I2[2 + i][j] = mfma_i8(af[i][0], bf[j][1], I2[2 + i][j]);
        I2[2 + i][j] = mfma_i8(af[i][1], bf[j][0], I2[2 + i][j]);
      }
    __builtin_amdgcn_s_setprio(0);
    if (pf) { asm volatile("s_waitcnt vmcnt(6)" ::: "memory"); }
    else    { asm volatile("s_waitcnt vmcnt(0)" ::: "memory"); }
    __builtin_amdgcn_s_barrier();
  }

  const int fq4 = fg << 2;
  if constexpr (STORE == 0) {
    // ---- dequant + bias (+relu) -> split-bf16 via LDS bounce, NT stores ----
    short* ldsS = (short*)lds8;
    short* Oh = (short*)(ws + o0);
    short* Ol = (short*)(ws + o1);
#pragma unroll
    for (int rd = 0; rd < 2; ++rd) {
      __builtin_amdgcn_s_barrier();
#pragma unroll
      for (int i = 0; i < 4; ++i) {
        const int rl = wm + i * 16 + fq4;
        const f32x4 sa4 = *(const f32x4*)&AS[brow + rl];
#pragma unroll
        for (int j = 0; j < 4; ++j) {
          const int cl = wn + j * 16 + fr;
          const float sb = BS[bcol + cl];
          const float bv = bias ? bias[bcol + cl] : 0.0f;
#pragma unroll
          for (int e = 0; e < 4; ++e) {
            float u = ((float)I1[i][j][e] + (float)I2[i][j][e] * (1.0f / 256.0f)) *
                          (sa4[e] * sb) + bv;
            if (RELU) u = fmaxf(u, 0.0f);
            short v;
            if (rd == 0) {
              v = f2bf(u);
            } else {
              const short hb = f2bf(u);
              v = f2bf(u - bf2f(hb));
            }
            ldsS[(rl + e) * 264 + cl] = v;
          }
        }
      }
      __builtin_amdgcn_s_barrier();
      short* gout = (rd == 0) ? Oh : Ol;
#pragma unroll
      for (int gi = 0; gi < 8; ++gi) {
        const int g = gi * 512 + tid;
        const int row = g >> 5, cg = g & 31;
        const short8 v = *(const short8*)&ldsS[row * 264 + cg * 8];
        nts(v, (short8*)&gout[(size_t)(brow + row) * N + bcol + cg * 8]);
      }
    }
  } else {
    // ---- dequant -> fp32 TRANSPOSED ST[n][m] via LDS bounce, NT stores ----
    float* Of = (float*)(ws + o0) + (size_t)bz * M * N;
    float* ldsf = (float*)lds8;
#pragma unroll
    for (int h2 = 0; h2 < 2; ++h2) {
      __builtin_amdgcn_s_barrier();
      if ((wn >> 7) == h2) {
#pragma unroll
        for (int i = 0; i < 4; ++i) {
          const int rl = wm + i * 16 + fq4;
          const f32x4 sa4 = *(const f32x4*)&AS[brow + rl];
#pragma unroll
          for (int j = 0; j < 4; ++j) {
            const int cp = (wn & 127) + j * 16 + fr;
            const float sb = BS[bcol + wn + j * 16 + fr];
            f32x4 u;
#pragma unroll
            for (int e = 0; e < 4; ++e)
              u[e] = ((float)I1[i][j][e] + (float)I2[i][j][e] * (1.0f / 256.0f)) *
                     (sa4[e] * sb);
            *(f32x4*)&ldsf[cp * 132 + rl] = u;
          }
        }
      }
      __builtin_amdgcn_s_barrier();
#pragma unroll
      for (int gi = 0; gi < 8; ++gi) {
        const int g = gi * 512 + tid;
        const int tr = g >> 5, tc4 = (g & 31) << 2;
        const f32x4 v = *(const f32x4*)&ldsf[tr * 132 + tc4];
        nts(v, (f32x4*)&Of[(size_t)(bcol + h2 * 128 + tr) * M + brow + tc4]);
      }
    }
  }
}

// ---------------------------------------------------------------------------
// 256x256-tile 8-wave pipelined bf16 GEMM, 2 phases per K-tile (round-4 core).
// NAB=1 plain bf16, BK=64. STORE: 1 bf16 out, 3 fp32 optr bounce. NT stores.
// ---------------------------------------------------------------------------
constexpr int CH = 8192;        // shorts per 16KB chunk

DEV short8 read_frag1(const short* base, int row, int s, int fg) {
  return *(const short8*)&base[row * 64 + ((((s << 2) | fg) ^ (row & 7)) << 3)];
}

DEV f32x4 mfma16(short8 a, short8 b, f32x4 c) {
  return __builtin_amdgcn_mfma_f32_16x16x32_bf16(a, b, c, 0, 0, 0);
}

template <bool RELU, int STORE>
__launch_bounds__(512, 2)
__global__ void gemm8_k(unsigned char* wsb,
                        size_t aoff0, size_t boff0,
                        const float* __restrict__ bias,
                        size_t ooff0, float* __restrict__ optr,
                        int M, int N, int K, int gx, int gxy) {
  __shared__ alignas(16) short lds[10 * CH];

  unsigned char* ws = wsbase(wsb);
  const int tid = threadIdx.x;
  const int lane = tid & 63;
  const int wave = tid >> 6;
  const int wm = (wave >> 2) << 7;   // 0 / 128
  const int wn = (wave & 3) << 6;    // 0 / 64 / 128 / 192

  const int nwg = gridDim.x;
  const int q8 = nwg >> 3;
  const int id = (blockIdx.x & 7) * q8 + (blockIdx.x >> 3);
  const int bz = id / gxy;
  const int rem = id - bz * gxy;
  const int by = rem / gx;
  const int bx = rem - by * gx;
  const int brow = by << 8;
  const int bcol = bx << 8;

  const short* A0 = (const short*)(ws + aoff0) + (size_t)bz * M * K;
  const short* B0g = (const short*)(ws + boff0) + (size_t)bz * N * K;

  size_t aSrc[2][2], bSrc[2][2];
#pragma unroll
  for (int h = 0; h < 2; ++h) {
    const int G = tid + h * 512;
    const int r = G >> 3, c = G & 7;
#pragma unroll
    for (int qq = 0; qq < 2; ++qq) {
      aSrc[qq][h] = (size_t)(brow + qq * 128 + r) * K + (size_t)((c ^ (r & 7)) << 3);
      bSrc[qq][h] = (size_t)(bcol + qq * 128 + r) * K + (size_t)((c ^ (r & 7)) << 3);
    }
  }
  const int ldst0 = tid << 3;

  auto issueA = [&](int slot, int qq, int tt) {
    short* dst = &lds[slot + qq * CH];
    const size_t ka = (size_t)tt * 64;
    gl16(A0 + aSrc[qq][0] + ka, dst + ldst0);
    gl16(A0 + aSrc[qq][1] + ka, dst + ldst0 + CH / 2);
  };
  auto issueB = [&](int slot, int qq, int tt) {
    short* dst = &lds[slot + qq * CH];
    const size_t ka = (size_t)tt * 64;
    gl16(B0g + bSrc[qq][0] + ka, dst + ldst0);
    gl16(B0g + bSrc[qq][1] + ka, dst + ldst0 + CH / 2);
  };

  const int nt = K / 64;
  const int fr = lane & 15;
  const int fg = lane >> 4;

  f32x4 acc[8][4] = {};

  issueA(0, 0, 0); issueA(0, 1, 0);
  issueB(6 * CH, 0, 0); issueB(6 * CH, 1, 0);
  if (nt > 1) {
    issueA(2 * CH, 0, 1); issueA(2 * CH, 1, 1);
    issueB(8 * CH, 0, 1); issueB(8 * CH, 1, 1);
    asm volatile("s_waitcnt vmcnt(8)" ::: "memory");
  } else {
    asm volatile("s_waitcnt vmcnt(0)" ::: "memory");
  }
  __builtin_amdgcn_s_barrier();

  for (int t = 0; t < nt; ++t) {
    const short* aBase = &lds[(t % 3) * (2 * CH)];
    const short* bBase = &lds[6 * CH + (t & 1) * (2 * CH)];
    const int sA2 = ((t + 2) % 3) * (2 * CH);
    const int sB  = 6 * CH + (t & 1) * (2 * CH);
    const bool pf = (t + 2 < nt);
    short8 bfr[4][2], av[4][2];

    if (pf) { issueA(sA2, 0, t + 2); issueA(sA2, 1, t + 2); }
#pragma unroll
    for (int j = 0; j < 4; ++j) {
      bfr[j][0] = read_frag1(bBase, wn + j * 16 + fr, 0, fg);
      bfr[j][1] = read_frag1(bBase, wn + j * 16 + fr, 1, fg);
    }
#pragma unroll
    for (int i = 0; i < 4; ++i) {
      av[i][0] = read_frag1(aBase, wm + i * 16 + fr, 0, fg);
      av[i][1] = read_frag1(aBase, wm + i * 16 + fr, 1, fg);
    }
    __builtin_amdgcn_s_setprio(1);
#pragma unroll
    for (int i = 0; i < 4; ++i)
#pragma unroll
      for (int j = 0; j < 4; ++j) {
        acc[i][j] = mfma16(av[i][0], bfr[j][0], acc[i][j]);
        acc[i][j] = mfma16(av[i][1], bfr[j][1], acc[i][j]);
      }
    __builtin_amdgcn_s_setprio(0);
    __builtin_amdgcn_s_barrier();

    asm volatile("" ::: "memory");
    if (pf) { issueB(sB, 0, t + 2); issueB(sB, 1, t + 2); }
#pragma unroll
    for (int i = 0; i < 4; ++i) {
      av[i][0] = read_frag1(aBase, wm + 64 + i * 16 + fr, 0, fg);
      av[i][1] = read_frag1(aBase, wm + 64 + i * 16 + fr, 1, fg);
    }
    __builtin_amdgcn_s_setprio(1);
#pragma unroll
    for (int i = 0; i < 4; ++i)
#pragma unroll
      for (int j = 0; j < 4; ++j) {
        acc[4 + i][j] = mfma16(av[i][0], bfr[j][0], acc[4 + i][j]);
        acc[4 + i][j] = mfma16(av[i][1], bfr[j][1], acc[4 + i][j]);
      }
    __builtin_amdgcn_s_setprio(0);
    if (pf) {
      asm volatile("s_waitcnt vmcnt(8)" ::: "memory");
    } else {
      asm volatile("s_waitcnt vmcnt(0)" ::: "memory");
    }
    __builtin_amdgcn_s_barrier();
  }

  // ---- epilogue ----
  const int fq4 = (lane >> 4) << 2;
  if constexpr (STORE == 1) {
    short* Oh = (short*)(ws + ooff0);
    __builtin_amdgcn_s_barrier();
#pragma unroll
    for (int i = 0; i < 8; ++i) {
      const int rl = wm + i * 16 + fq4;
#pragma unroll
      for (int j = 0; j < 4; ++j) {
        const int cl = wn + j * 16 + fr;
        const float bv = bias ? bias[bcol + cl] : 0.0f;
#pragma unroll
        for (int e = 0; e < 4; ++e) {
          float u = acc[i][j][e] + bv;
          if (RELU) u = fmaxf(u, 0.0f);
          lds[(rl + e) * 264 + cl] = f2bf(u);
        }
      }
    }
    __builtin_amdgcn_s_barrier();
#pragma unroll
    for (int gi = 0; gi < 16; ++gi) {
      const int g = gi * 512 + tid;
      const int row = g >> 5, cg = g & 31;
      const short8 v = *(const short8*)&lds[row * 264 + cg * 8];
      nts(v, (short8*)&Oh[(size_t)(brow + row) * N + bcol + cg * 8]);
    }
  } else {
    float* Op = optr + (size_t)bz * M * N;
    float* ldsf = (float*)lds;
#pragma unroll
    for (int h = 0; h < 2; ++h) {
      __builtin_amdgcn_s_barrier();
      if ((wm & 128) == (h << 7)) {
#pragma unroll
        for (int i = 0; i < 8; ++i) {
          const int rp = (wm & 127) + i * 16 + fq4;
#pragma unroll
          for (int j = 0; j < 4; ++j) {
            const int cl = wn + j * 16 + fr;
#pragma unroll
            for (int e = 0; e < 4; ++e)
              ldsf[(rp + e) * 258 + cl] = acc[i][j][e];
          }
        }
      }
      __builtin_amdgcn_s_barrier();
#pragma unroll
      for (int gi = 0; gi < 16; ++gi) {
        const int g = gi * 512 + tid;
        const int tr = g >> 6, tc4 = (g & 63) << 2;
        const f32x4 v = *(const f32x4*)&ldsf[tr * 258 + tc4];
        nts(v, (f32x4*)&Op[(size_t)(brow + h * 128 + tr) * N + bcol + tc4]);
      }
    }
  }
}

// ---------------------------------------------------------------------------
// row softmax over ST rows (axis-1 softmax of scores), output bf16 probs^T
// ST read-once -> nt loads; PT streaming -> nt stores
// ---------------------------------------------------------------------------
__launch_bounds__(256)
__global__ void softmax_rows_k(unsigned char* wsb, size_t st, size_t pt) {
  constexpr int S = 2048;
  unsigned char* ws = wsbase(wsb);
  const f32x4* row = (const f32x4*)((const float*)(ws + st) + (size_t)blockIdx.x * S);
  short4v* out = (short4v*)((short*)(ws + pt) + (size_t)blockIdx.x * S);
  const int tid = threadIdx.x, lane = tid & 63, wv = tid >> 6;
  const f32x4 a = ntl(&row[tid]);
  const f32x4 b = ntl(&row[tid + 256]);
  float m = fmaxf(fmaxf(fmaxf(a[0], a[1]), fmaxf(a[2], a[3])),
                  fmaxf(fmaxf(b[0], b[1]), fmaxf(b[2], b[3])));
#pragma unroll
  for (int o = 32; o; o >>= 1) m = fmaxf(m, __shfl_xor(m, o));
  __shared__ float rb[8];
  if (lane == 0) rb[wv] = m;
  __syncthreads();
  m = fmaxf(fmaxf(rb[0], rb[1]), fmaxf(rb[2], rb[3]));
  float e[8];
  float s = 0.0f;
#pragma unroll
  for (int q = 0; q < 4; ++q) { e[q] = expf(a[q] - m); s += e[q]; }
#pragma unroll
  for (int q = 0; q < 4; ++q) { e[4 + q] = expf(b[q] - m); s += e[4 + q]; }
#pragma unroll
  for (int o = 32; o; o >>= 1) s += __shfl_xor(s, o);
  if (lane == 0) rb[4 + wv] = s;
  __syncthreads();
  s = rb[4] + rb[5] + rb[6] + rb[7];
  const float inv = 1.0f / s;
  short4v o1, o2;
#pragma unroll
  for (int q = 0; q < 4; ++q) { o1[q] = f2bf(e[q] * inv); o2[q] = f2bf(e[4 + q] * inv); }
  nts(o1, &out[tid]);
  nts(o2, &out[tid + 256]);
}

// ---------------------------------------------------------------------------
extern "C" void kernel_launch(void* const* d_in, const int* in_sizes, int n_in,
                              void* d_out, int out_size, void* d_ws, size_t ws_size,
                              hipStream_t stream) {
  const float* x   = (const float*)d_in[0];
  const float* qw1 = (const float*)d_in[1];
  const float* qb1 = (const float*)d_in[2];
  const float* qw2 = (const float*)d_in[3];
  const float* qb2 = (const float*)d_in[4];
  const float* kw1 = (const float*)d_in[5];
  const float* kb1 = (const float*)d_in[6];
  const float* kw2 = (const float*)d_in[7];
  const float* kb2 = (const float*)d_in[8];
  const float* vw1 = (const float*)d_in[9];
  const float* vb1 = (const float*)d_in[10];
  const float* vw2 = (const float*)d_in[11];
  const float* vb2 = (const float*)d_in[12];
  float* out = (float*)d_out;
  unsigned char* wsb = (ws_size >= WS_TOTAL) ? (unsigned char*)d_ws : nullptr;
  unsigned char* wsr;
  if (wsb) wsr = wsb;
  else { hipError_t e = hipGetSymbolAddress((void**)&wsr, HIP_SYMBOL(g_ws)); (void)e; }

  const int M = BB * SS;  // 8192
  dim3 blk(512);
  dim3 tb(32, 8);

  // x -> i8 2-level (Q/K MLP1) and bf16 hi (V MLP1)
  quant_x_k<<<8192, 256, 0, stream>>>(x, wsb, OFF_XA1, OFF_XA2, OFF_XS);
  cast_hi_k<<<4096, 256, 0, stream>>>(x, wsb, OFF_XH, NX / 4);

  // ================= Q path (all i8) =================
  hipMemsetAsync(wsr + OFF_CM, 0, 32768, stream);
  colmax_k<<<dim3(HHID / 256, DD / 128), 256, 0, stream>>>(qw1, wsb, OFF_CM, DD, HHID);
  scalefix_k<<<32, 256, 0, stream>>>(wsb, OFF_CM, HHID);
  transpose_quant_k<<<dim3(HHID / 32, DD / 32), tb, 0, stream>>>(qw1, wsb, OFF_WA1, OFF_WA2, OFF_CM, DD, HHID);
  gemm_i8_k<true, 0><<<2048, blk, 0, stream>>>(wsb, OFF_XA1, OFF_XA2, OFF_WA1, OFF_WA2,
                                               OFF_XS, OFF_CM, qb1, OFF_HH, OFF_HL,
                                               M, HHID, DD, 32, 2048);
  rowquant_k<<<8192, 1024, 0, stream>>>(wsb, OFF_HH, OFF_HL, OFF_HA1, OFF_HA2, OFF_HS, HHID);
  hipMemsetAsync(wsr + OFF_CM, 0, 32768, stream);
  colmax_k<<<dim3(DD / 256, HHID / 128), 256, 0, stream>>>(qw2, wsb, OFF_CM, HHID, DD);
  scalefix_k<<<8, 256, 0, stream>>>(wsb, OFF_CM, DD);
  transpose_quant_k<<<dim3(DD / 32, HHID / 32), tb, 0, stream>>>(qw2, wsb, OFF_WA1, OFF_WA2, OFF_CM, HHID, DD);
  gemm_i8_k<false, 0><<<512, blk, 0, stream>>>(wsb, OFF_HA1, OFF_HA2, OFF_WA1, OFF_WA2,
                                               OFF_HS, OFF_CM, qb2, OFF_QKH, OFF_QKL,
                                               M, DD, HHID, 8, 512);
  rowquant_k<<<8192, 256, 0, stream>>>(wsb, OFF_QKH, OFF_QKL, OFF_QA1, OFF_QA2, OFF_QS, DD);

  // ================= K path (all i8) =================
  hipMemsetAsync(wsr + OFF_CM, 0, 32768, stream);
  colmax_k<<<dim3(HHID / 256, DD / 128), 256, 0, stream>>>(kw1, wsb, OFF_CM, DD, HHID);
  scalefix_k<<<32, 256, 0, stream>>>(wsb, OFF_CM, HHID);
  transpose_quant_k<<<dim3(HHID / 32, DD / 32), tb, 0, stream>>>(kw1, wsb, OFF_WA1, OFF_WA2, OFF_CM, DD, HHID);
  gemm_i8_k<true, 0><<<2048, blk, 0, stream>>>(wsb, OFF_XA1, OFF_XA2, OFF_WA1, OFF_WA2,
                                               OFF_XS, OFF_CM, kb1, OFF_HH, OFF_HL,
                                               M, HHID, DD, 32, 2048);
  rowquant_k<<<8192, 1024, 0, stream>>>(wsb, OFF_HH, OFF_HL, OFF_HA1, OFF_HA2, OFF_HS, HHID);
  hipMemsetAsync(wsr + OFF_CM, 0, 32768, stream);
  colmax_k<<<dim3(DD / 256, HHID / 128), 256, 0, stream>>>(kw2, wsb, OFF_CM, HHID, DD);
  scalefix_k<<<8, 256, 0, stream>>>(wsb, OFF_CM, DD);
  transpose_quant_k<<<dim3(DD / 32, HHID / 32), tb, 0, stream>>>(kw2, wsb, OFF_WA1, OFF_WA2, OFF_CM, HHID, DD);
  gemm_i8_k<false, 0><<<512, blk, 0, stream>>>(wsb, OFF_HA1, OFF_HA2, OFF_WA1, OFF_WA2,
                                               OFF_HS, OFF_CM, kb2, OFF_QKH, OFF_QKL,
                                               M, DD, HHID, 8, 512);
  rowquant_k<<<8192, 256, 0, stream>>>(wsb, OFF_QKH, OFF_QKL, OFF_KA1, OFF_KA2, OFF_KS, DD);

  // ================= V path (plain bf16) =================
  transpose_cast_k<<<dim3(HHID / 32, DD / 32), tb, 0, stream>>>(vw1, wsb, OFF_WHV, DD, HHID);
  gemm8_k<true, 1><<<1024, blk, 0, stream>>>(
      wsb, OFF_XH, OFF_WHV, vb1, OFF_HH, nullptr, M, HHID, DD, 32, 1024);
  transpose_cast_k<<<dim3(DD / 32, HHID / 32), tb, 0, stream>>>(vw2, wsb, OFF_WHV, HHID, DD);
  gemm8_k<false, 1><<<256, blk, 0, stream>>>(
      wsb, OFF_HH, OFF_WHV, vb2, OFF_V, nullptr, M, DD, HHID, 8, 256);

  // ---- scores^T (i8, batched): ST[t][s] per batch ----
  gemm_i8_k<false, 2><<<512, blk, 0, stream>>>(wsb, OFF_QA1, OFF_QA2, OFF_KA1, OFF_KA2,
                                               OFF_QS, OFF_KS, nullptr, OFF_ST, 0,
                                               SS, SS, DD, 8, 128);

  // ---- softmax over axis 1 == row softmax of ST; writes bf16 probs^T ----
  softmax_rows_k<<<BB * SS, 256, 0, stream>>>(wsb, OFF_ST, OFF_PT);

  // ---- out = V @ probs  (B^T = probs^T), fp32 to d_out ----
  gemm8_k<false, 3><<<256, blk, 0, stream>>>(
      wsb, OFF_V, OFF_PT, nullptr, 0, out, SS, SS, DD, 8, 64);
}

// Round 9
// 2671.006 us; speedup vs baseline: 1.4644x; 1.0243x over previous
//
#include <hip/hip_runtime.h>
#include <cstdint>
#include <cstddef>

typedef __attribute__((ext_vector_type(8))) short short8;
typedef __attribute__((ext_vector_type(4))) short short4v;
typedef __attribute__((ext_vector_type(4))) float f32x4;
typedef __attribute__((ext_vector_type(4))) int i32x4;

#define DEV __device__ __forceinline__

// Problem geometry (fixed by the reference)
constexpr int DD = 2048;           // D
constexpr int HHID = 8192;         // H
constexpr int BB = 4;              // B
constexpr int SS = 2048;           // S
constexpr size_t NX = (size_t)BB * SS * DD;   // 16,777,216
constexpr size_t NW = (size_t)DD * HHID;      // 16,777,216
constexpr size_t NH = (size_t)BB * SS * HHID; // 67,108,864

// Scratch layout (bytes)
constexpr size_t OFF_XH  = 0;                    // x bf16 hi (V path)
constexpr size_t OFF_XA1 = OFF_XH + NX * 2;      // x i8 lvl1
constexpr size_t OFF_XA2 = OFF_XA1 + NX;         // x i8 lvl2
constexpr size_t OFF_WA1 = OFF_XA2 + NX;         // weight i8 lvl1 (reused 4x)
constexpr size_t OFF_WA2 = OFF_WA1 + NW;         // weight i8 lvl2
constexpr size_t OFF_WHV = OFF_WA1;              // alias: V-path bf16 weights (NW*2)
constexpr size_t OFF_HH  = OFF_WA2 + NW;         // h bf16 hi / hV bf16 / ST alias
constexpr size_t OFF_HL  = OFF_HH + NH * 2;      // h bf16 lo / PT alias
constexpr size_t OFF_QKH = OFF_HL + NH * 2;      // Q-then-K split hi (reused)
constexpr size_t OFF_QKL = OFF_QKH + NX * 2;
constexpr size_t OFF_QA1 = OFF_QKL + NX * 2;     // Q i8
constexpr size_t OFF_QA2 = OFF_QA1 + NX;
constexpr size_t OFF_KA1 = OFF_QA2 + NX;         // K i8
constexpr size_t OFF_KA2 = OFF_KA1 + NX;
constexpr size_t OFF_HA1 = OFF_KA2 + NX;         // h i8 (reused Q/K paths)
constexpr size_t OFF_HA2 = OFF_HA1 + NH;
constexpr size_t OFF_V   = OFF_HA2 + NH;         // V bf16
constexpr size_t OFF_XS  = OFF_V + NX * 2;       // f32[8192] x row scales
constexpr size_t OFF_HS  = OFF_XS + 32768;       // f32[8192] h row scales
constexpr size_t OFF_QS  = OFF_HS + 32768;       // f32[8192] Q row scales
constexpr size_t OFF_KS  = OFF_QS + 32768;       // f32[8192] K row scales
constexpr size_t OFF_CM  = OFF_KS + 32768;       // colmax scratch (reused 4x)
constexpr size_t WS_TOTAL = OFF_CM + 32768;
constexpr size_t OFF_ST = OFF_HH;                // fp32 scores^T
constexpr size_t OFF_PT = OFF_HL;                // bf16 probs^T

__device__ __align__(256) unsigned char g_ws[WS_TOTAL];

DEV unsigned char* wsbase(unsigned char* p) { return p ? p : (unsigned char*)g_ws; }
DEV short f2bf(float v) { __bf16 b = (__bf16)v; return __builtin_bit_cast(short, b); }
DEV float bf2f(short s) { return (float)__builtin_bit_cast(__bf16, s); }

template <typename T> DEV void nts(T v, T* p) { __builtin_nontemporal_store(v, p); }
template <typename T> DEV T ntl(const T* p) { return __builtin_nontemporal_load(p); }

DEV void gl16(const short* g, short* l) {
  __builtin_amdgcn_global_load_lds((const __attribute__((address_space(1))) void*)g,
                                   (__attribute__((address_space(3))) void*)l, 16, 0, 0);
}
DEV void gl16b(const signed char* g, signed char* l) {
  __builtin_amdgcn_global_load_lds((const __attribute__((address_space(1))) void*)g,
                                   (__attribute__((address_space(3))) void*)l, 16, 0, 0);
}

// grouped-row raster: rem in [0, gy*gx) -> (by, bx) with grp-row groups so
// the ~32 concurrently-resident blocks of an XCD form a 2D window (grp rows
// x 32/grp cols) -> both operand panels' K-slices are shared in L2.
DEV void raster2d(int rem, int gx, int grp, int& by, int& bx) {
  const int tpg = grp * gx;
  const int gidx = rem / tpg;
  const int o = rem - gidx * tpg;
  const int r = o / grp;
  by = gidx * grp + (o - r * grp);
  bx = r;
}

// ---------------------------------------------------------------------------
// cast x -> bf16 hi (V path)
// ---------------------------------------------------------------------------
__global__ void cast_hi_k(const float* __restrict__ x, unsigned char* wsb,
                          size_t oh, size_t n4) {
  unsigned char* ws = wsbase(wsb);
  short4v* OH = (short4v*)(ws + oh);
  const f32x4* X = (const f32x4*)x;
  for (size_t i = (size_t)blockIdx.x * blockDim.x + threadIdx.x; i < n4;
       i += (size_t)gridDim.x * blockDim.x) {
    const f32x4 v = ntl(&X[i]);
    short4v hs;
#pragma unroll
    for (int e = 0; e < 4; ++e) hs[e] = f2bf(v[e]);
    OH[i] = hs;
  }
}

// ---------------------------------------------------------------------------
// per-row 2-level i8 quantization of fp32 x (rowlen 2048)
// ---------------------------------------------------------------------------
__launch_bounds__(256)
__global__ void quant_x_k(const float* __restrict__ x, unsigned char* wsb,
                          size_t oa1, size_t oa2, size_t oxs) {
  unsigned char* ws = wsbase(wsb);
  signed char* A1 = (signed char*)(ws + oa1);
  signed char* A2 = (signed char*)(ws + oa2);
  float* XS = (float*)(ws + oxs);
  const int row = blockIdx.x;
  const float* xr = x + (size_t)row * 2048;
  const int tid = threadIdx.x, lane = tid & 63;
  const f32x4 v0 = *(const f32x4*)&xr[tid * 8];
  const f32x4 v1 = *(const f32x4*)&xr[tid * 8 + 4];
  float m = 0.0f;
#pragma unroll
  for (int e = 0; e < 4; ++e) m = fmaxf(m, fmaxf(fabsf(v0[e]), fabsf(v1[e])));
#pragma unroll
  for (int o = 32; o; o >>= 1) m = fmaxf(m, __shfl_xor(m, o));
  __shared__ float rb[4];
  if (lane == 0) rb[tid >> 6] = m;
  __syncthreads();
  m = fmaxf(fmaxf(rb[0], rb[1]), fmaxf(rb[2], rb[3]));
  const float inv = (m > 1e-30f) ? 127.0f / m : 0.0f;
  if (tid == 0) XS[row] = m * (1.0f / 127.0f);
  unsigned int w1a = 0, w1b = 0, w2a = 0, w2b = 0;
#pragma unroll
  for (int e = 0; e < 8; ++e) {
    const float xv = (e < 4) ? v0[e] : v1[e - 4];
    const float q = xv * inv;
    const float a1f = rintf(q);
    int ia2 = (int)rintf((q - a1f) * 256.0f);
    ia2 = ia2 > 127 ? 127 : (ia2 < -127 ? -127 : ia2);
    const unsigned int b1 = (unsigned char)(signed char)(int)a1f;
    const unsigned int b2 = (unsigned char)(signed char)ia2;
    if (e < 4) { w1a |= b1 << (8 * e); w2a |= b2 << (8 * e); }
    else       { w1b |= b1 << (8 * (e - 4)); w2b |= b2 << (8 * (e - 4)); }
  }
  const size_t o = (size_t)row * 2048 + tid * 8;
  *(unsigned int*)&A1[o] = w1a; *(unsigned int*)&A1[o + 4] = w1b;
  *(unsigned int*)&A2[o] = w2a; *(unsigned int*)&A2[o + 4] = w2b;
}

// ---------------------------------------------------------------------------
// per-row 2-level i8 quantization of split-bf16 (hi+lo) matrix rows.
// ---------------------------------------------------------------------------
__launch_bounds__(1024)
__global__ void rowquant_k(unsigned char* wsb, size_t hho, size_t hlo,
                           size_t oa1, size_t oa2, size_t oso, int rowlen) {
  unsigned char* ws = wsbase(wsb);
  const int row = blockIdx.x, tid = threadIdx.x, lane = tid & 63, wv = tid >> 6;
  const int nw = blockDim.x >> 6;
  const short8 hi = ntl((const short8*)((const short*)(ws + hho) + (size_t)row * rowlen) + tid);
  const short8 lo = ntl((const short8*)((const short*)(ws + hlo) + (size_t)row * rowlen) + tid);
  float v[8]; float m = 0.0f;
#pragma unroll
  for (int e = 0; e < 8; ++e) {
    v[e] = bf2f(hi[e]) + bf2f(lo[e]);
    m = fmaxf(m, fabsf(v[e]));
  }
#pragma unroll
  for (int o = 32; o; o >>= 1) m = fmaxf(m, __shfl_xor(m, o));
  __shared__ float rb[16];
  if (lane == 0) rb[wv] = m;
  __syncthreads();
  m = rb[0];
  for (int i = 1; i < nw; ++i) m = fmaxf(m, rb[i]);
  const float inv = (m > 1e-30f) ? 127.0f / m : 0.0f;
  if (tid == 0) ((float*)(ws + oso))[row] = m * (1.0f / 127.0f);
  unsigned int w1a = 0, w1b = 0, w2a = 0, w2b = 0;
#pragma unroll
  for (int e = 0; e < 8; ++e) {
    const float q = v[e] * inv;
    const float a1f = rintf(q);
    int ia2 = (int)rintf((q - a1f) * 256.0f);
    ia2 = ia2 > 127 ? 127 : (ia2 < -127 ? -127 : ia2);
    const unsigned int b1 = (unsigned char)(signed char)(int)a1f;
    const unsigned int b2 = (unsigned char)(signed char)ia2;
    if (e < 4) { w1a |= b1 << (8 * e); w2a |= b2 << (8 * e); }
    else       { w1b |= b1 << (8 * (e - 4)); w2b |= b2 << (8 * (e - 4)); }
  }
  const size_t o = (size_t)row * rowlen + tid * 8;
  signed char* A1 = (signed char*)(ws + oa1);
  signed char* A2 = (signed char*)(ws + oa2);
  *(unsigned int*)&A1[o] = w1a; *(unsigned int*)&A1[o + 4] = w1b;
  *(unsigned int*)&A2[o] = w2a; *(unsigned int*)&A2[o + 4] = w2b;
}

// ---------------------------------------------------------------------------
// per-column absmax of w [R][C] -> MX[col]
// ---------------------------------------------------------------------------
__launch_bounds__(256)
__global__ void colmax_k(const float* __restrict__ w, unsigned char* wsb,
                         size_t omax, int R, int C) {
  unsigned char* ws = wsbase(wsb);
  unsigned int* MX = (unsigned int*)(ws + omax);
  const int col = blockIdx.x * 256 + threadIdx.x;
  const int r0 = blockIdx.y * 128;
  float m = 0.0f;
  for (int r = 0; r < 128; ++r) m = fmaxf(m, fabsf(w[(size_t)(r0 + r) * C + col]));
  atomicMax(&MX[col], __float_as_uint(m));
}

// in-place: uint-encoded absmax -> f32 scale (max/127)
__global__ void scalefix_k(unsigned char* wsb, size_t off, int n) {
  unsigned char* ws = wsbase(wsb);
  const int i = blockIdx.x * 256 + threadIdx.x;
  if (i < n) {
    float* p = (float*)(ws + off);
    const unsigned int u = ((const unsigned int*)p)[i];
    p[i] = __uint_as_float(u) * (1.0f / 127.0f);
  }
}

// ---------------------------------------------------------------------------
// transpose + 2-level i8 quant: src R x C fp32 -> a1,a2 [C][R] i8
// ---------------------------------------------------------------------------
__global__ void transpose_quant_k(const float* __restrict__ src, unsigned char* wsb,
                                  size_t oa1, size_t oa2, size_t osc, int R, int C) {
  __shared__ float t[32][33];
  unsigned char* ws = wsbase(wsb);
  signed char* A1 = (signed char*)(ws + oa1);
  signed char* A2 = (signed char*)(ws + oa2);
  const float* SC = (const float*)(ws + osc);
  const int c0 = blockIdx.x << 5, r0 = blockIdx.y << 5;
  const int x = threadIdx.x, y = threadIdx.y;
#pragma unroll
  for (int i = 0; i < 4; ++i) {
    const int rr = y + (i << 3);
    t[rr][x] = ntl(&src[(size_t)(r0 + rr) * C + c0 + x]);
  }
  __syncthreads();
#pragma unroll
  for (int i = 0; i < 4; ++i) {
    const int oc = y + (i << 3);
    const float v = t[x][oc];
    const float s = SC[c0 + oc];
    const float inv = (s > 1e-38f) ? 1.0f / s : 0.0f;
    const float q = v * inv;
    const float a1f = rintf(q);
    int ia2 = (int)rintf((q - a1f) * 256.0f);
    ia2 = ia2 > 127 ? 127 : (ia2 < -127 ? -127 : ia2);
    const size_t o = (size_t)(c0 + oc) * R + r0 + x;
    A1[o] = (signed char)(int)a1f;
    A2[o] = (signed char)ia2;
  }
}

// ---------------------------------------------------------------------------
// transpose + cast: src R x C fp32 -> out C x R bf16 hi (V path weights)
// ---------------------------------------------------------------------------
__global__ void transpose_cast_k(const float* __restrict__ src, unsigned char* wsb,
                                 size_t oh, int R, int C) {
  __shared__ float t[32][33];
  unsigned char* ws = wsbase(wsb);
  short* OH = (short*)(ws + oh);
  const int c0 = blockIdx.x << 5, r0 = blockIdx.y << 5;
  const int x = threadIdx.x, y = threadIdx.y;
#pragma unroll
  for (int i = 0; i < 4; ++i) {
    const int rr = y + (i << 3);
    t[rr][x] = ntl(&src[(size_t)(r0 + rr) * C + c0 + x]);
  }
  __syncthreads();
#pragma unroll
  for (int i = 0; i < 4; ++i) {
    const int oc = y + (i << 3);
    OH[(size_t)(c0 + oc) * R + r0 + x] = f2bf(t[x][oc]);
  }
}

// ---------------------------------------------------------------------------
// 2-level i8 GEMM (as round 8) + grouped-row raster (grp).
// ---------------------------------------------------------------------------
DEV i32x4 mfma_i8(i32x4 a, i32x4 b, i32x4 c) {
  return __builtin_amdgcn_mfma_i32_16x16x64_i8(a, b, c, 0, 0, 0);
}
DEV i32x4 rfi8(const signed char* base, int lstride, int L, int row, int fg) {
  return *(const i32x4*)&base[L * lstride + row * 64 + ((fg ^ ((row >> 1) & 3)) << 4)];
}

template <bool RELU, int STORE>
__launch_bounds__(512, 2)
__global__ void gemm_i8_k(unsigned char* wsb,
                          size_t a1o, size_t a2o, size_t b1o, size_t b2o,
                          size_t aso, size_t bso, const float* __restrict__ bias,
                          size_t o0, size_t o1, int M, int N, int K,
                          int gx, int gxy, int grp) {
  __shared__ alignas(16) signed char lds8[114688];

  unsigned char* ws = wsbase(wsb);
  const int tid = threadIdx.x;
  const int lane = tid & 63;
  const int wave = tid >> 6;
  const int wm = (wave >> 2) << 6;   // 0 / 64
  const int wn = (wave & 3) << 6;    // 0 / 64 / 128 / 192
  const int fr = lane & 15;
  const int fg = lane >> 4;

  // bijective XCD swizzle (nwg multiple of 8) + grouped raster
  const int nwg = gridDim.x;
  const int q8 = nwg >> 3;
  const int id = (blockIdx.x & 7) * q8 + (blockIdx.x >> 3);
  const int bz = id / gxy;
  const int rem = id - bz * gxy;
  int by, bx;
  raster2d(rem, gx, grp, by, bx);
  const int brow = by << 7;    // 128-row tiles
  const int bcol = bx << 8;    // 256-col tiles

  const size_t batchA = (size_t)bz * M * K;
  const size_t batchB = (STORE == 2) ? (size_t)bz * N * K : 0;
  const signed char* Xa1 = (const signed char*)(ws + a1o) + batchA;
  const signed char* Xa2 = (const signed char*)(ws + a2o) + batchA;
  const signed char* Wa1 = (const signed char*)(ws + b1o) + batchB;
  const signed char* Wa2 = (const signed char*)(ws + b2o) + batchB;
  const float* AS = (const float*)(ws + aso) + (size_t)bz * M;
  const float* BS = (const float*)(ws + bso) + ((STORE == 2) ? (size_t)bz * N : 0);

  // staging source offsets (granule-swizzled, granule = 16 i8)
  const int ar = tid >> 2, ac = tid & 3;
  const size_t aOff = (size_t)(brow + ar) * K + ((ac ^ ((ar >> 1) & 3)) << 4);
  size_t bOff[2];
#pragma unroll
  for (int h = 0; h < 2; ++h) {
    const int G = tid + h * 512;
    const int r = G >> 2, c = G & 3;
    bOff[h] = (size_t)(bcol + r) * K + ((c ^ ((r >> 1) & 3)) << 4);
  }

  auto stageA = [&](int slotBase, int tt) {   // 2 gl16
    const int ko = tt * 64;
    gl16b(Xa1 + aOff + ko, &lds8[slotBase + (tid << 4)]);
    gl16b(Xa2 + aOff + ko, &lds8[slotBase + 8192 + (tid << 4)]);
  };
  auto stageB = [&](int slotBase, int tt) {   // 4 gl16
    const int ko = tt * 64;
#pragma unroll
    for (int h = 0; h < 2; ++h) {
      gl16b(Wa1 + bOff[h] + ko, &lds8[slotBase + ((tid + h * 512) << 4)]);
      gl16b(Wa2 + bOff[h] + ko, &lds8[slotBase + 16384 + ((tid + h * 512) << 4)]);
    }
  };

  const int nt = K / 64;
  i32x4 I1[4][4] = {};
  i32x4 I2[4][4] = {};

  // prologue: A0,B0,A1,B1
  stageA(0, 0);
  stageB(49152, 0);
  if (nt > 1) { stageA(16384, 1); stageB(49152 + 32768, 1); }
  if (nt > 1) { asm volatile("s_waitcnt vmcnt(6)" ::: "memory"); }
  else        { asm volatile("s_waitcnt vmcnt(0)" ::: "memory"); }
  __builtin_amdgcn_s_barrier();

  for (int t = 0; t < nt; ++t) {
    const signed char* aS = &lds8[(t % 3) * 16384];
    const signed char* bS = &lds8[49152 + (t & 1) * 32768];
    const int sA2 = ((t + 2) % 3) * 16384;
    const int sB2 = 49152 + (t & 1) * 32768;
    const bool pf = (t + 2 < nt);
    i32x4 bf[4][2], af[2][2];

    // ---- phase A: stage A(t+2); read all B frags + A rows 0-1; MFMA half 0 ----
    if (pf) stageA(sA2, t + 2);
#pragma unroll
    for (int j = 0; j < 4; ++j) {
      bf[j][0] = rfi8(bS, 16384, 0, wn + j * 16 + fr, fg);
      bf[j][1] = rfi8(bS, 16384, 1, wn + j * 16 + fr, fg);
    }
#pragma unroll
    for (int i = 0; i < 2; ++i) {
      af[i][0] = rfi8(aS, 8192, 0, wm + i * 16 + fr, fg);
      af[i][1] = rfi8(aS, 8192, 1, wm + i * 16 + fr, fg);
    }
    __builtin_amdgcn_s_setprio(1);
#pragma unroll
    for (int i = 0; i < 2; ++i)
#pragma unroll
      for (int j = 0; j < 4; ++j) {
        I1[i][j] = mfma_i8(af[i][0], bf[j][0], I1[i][j]);
        I2[i][j] = mfma_i8(af[i][0], bf[j][1], I2[i][j]);
        I2[i][j] = mfma_i8(af[i][1], bf[j][0], I2[i][j]);
      }
    __builtin_amdgcn_s_setprio(0);
    __builtin_amdgcn_s_barrier();

    // ---- phase B: stage B(t+2); read A rows 2-3; MFMA half 1; counted vmcnt ----
    asm volatile("" ::: "memory");
    if (pf) stageB(sB2, t + 2);
#pragma unroll
    for (int i = 0; i < 2; ++i) {
      af[i][0] = rfi8(aS, 8192, 0, wm + (2 + i) * 16 + fr, fg);
      af[i][1] = rfi8(aS, 8192, 1, wm + (2 + i) * 16 + fr, fg);
    }
    __builtin_amdgcn_s_setprio(1);
#pragma unroll
    for (int i = 0; i < 2; ++i)
#pragma unroll
      for (int j = 0; j < 4; ++j) {
        I1[2 + i][j] = mfma_i8(af[i][0], bf[j][0], I1[2 + i][j]);
        I2[2 + i][j] = mfma_i8(af[i][0], bf[j][1], I2[2 + i][j]);
        I2[2 + i][j] = mfma_i8(af[i][1], bf[j][0], I2[2 + i][j]);
      }
    __builtin_amdgcn_s_setprio(0);
    if (pf) { asm volatile("s_waitcnt vmcnt(6)" ::: "memory"); }
    else    { asm volatile("s_waitcnt vmcnt(0)" ::: "memory"); }
    __builtin_amdgcn_s_barrier();
  }

  const int fq4 = fg << 2;
  if constexpr (STORE == 0) {
    // ---- dequant + bias (+relu) -> split-bf16 via LDS bounce, NT stores ----
    short* ldsS = (short*)lds8;
    short* Oh = (short*)(ws + o0);
    short* Ol = (short*)(ws + o1);
#pragma unroll
    for (int rd = 0; rd < 2; ++rd) {
      __builtin_amdgcn_s_barrier();
#pragma unroll
      for (int i = 0; i < 4; ++i) {
        const int rl = wm + i * 16 + fq4;
        const f32x4 sa4 = *(const f32x4*)&AS[brow + rl];
#pragma unroll
        for (int j = 0; j < 4; ++j) {
          const int cl = wn + j * 16 + fr;
          const float sb = BS[bcol + cl];
          const float bv = bias ? bias[bcol + cl] : 0.0f;
#pragma unroll
          for (int e = 0; e < 4; ++e) {
            float u = ((float)I1[i][j][e] + (float)I2[i][j][e] * (1.0f / 256.0f)) *
                          (sa4[e] * sb) + bv;
            if (RELU) u = fmaxf(u, 0.0f);
            short v;
            if (rd == 0) {
              v = f2bf(u);
            } else {
              const short hb = f2bf(u);
              v = f2bf(u - bf2f(hb));
            }
            ldsS[(rl + e) * 264 + cl] = v;
          }
        }
      }
      __builtin_amdgcn_s_barrier();
      short* gout = (rd == 0) ? Oh : Ol;
#pragma unroll
      for (int gi = 0; gi < 8; ++gi) {
        const int g = gi * 512 + tid;
        const int row = g >> 5, cg = g & 31;
        const short8 v = *(const short8*)&ldsS[row * 264 + cg * 8];
        nts(v, (short8*)&gout[(size_t)(brow + row) * N + bcol + cg * 8]);
      }
    }
  } else {
    // ---- dequant -> fp32 TRANSPOSED ST[n][m] via LDS bounce, NT stores ----
    float* Of = (float*)(ws + o0) + (size_t)bz * M * N;
    float* ldsf = (float*)lds8;
#pragma unroll
    for (int h2 = 0; h2 < 2; ++h2) {
      __builtin_amdgcn_s_barrier();
      if ((wn >> 7) == h2) {
#pragma unroll
        for (int i = 0; i < 4; ++i) {
          const int rl = wm + i * 16 + fq4;
          const f32x4 sa4 = *(const f32x4*)&AS[brow + rl];
#pragma unroll
          for (int j = 0; j < 4; ++j) {
            const int cp = (wn & 127) + j * 16 + fr;
            const float sb = BS[bcol + wn + j * 16 + fr];
            f32x4 u;
#pragma unroll
            for (int e = 0; e < 4; ++e)
              u[e] = ((float)I1[i][j][e] + (float)I2[i][j][e] * (1.0f / 256.0f)) *
                     (sa4[e] * sb);
            *(f32x4*)&ldsf[cp * 132 + rl] = u;
          }
        }
      }
      __builtin_amdgcn_s_barrier();
#pragma unroll
      for (int gi = 0; gi < 8; ++gi) {
        const int g = gi * 512 + tid;
        const int tr = g >> 5, tc4 = (g & 31) << 2;
        const f32x4 v = *(const f32x4*)&ldsf[tr * 132 + tc4];
        nts(v, (f32x4*)&Of[(size_t)(bcol + h2 * 128 + tr) * M + brow + tc4]);
      }
    }
  }
}

// ---------------------------------------------------------------------------
// 256x256-tile 8-wave pipelined bf16 GEMM + grouped raster (grp).
// ---------------------------------------------------------------------------
constexpr int CH = 8192;        // shorts per 16KB chunk

DEV short8 read_frag1(const short* base, int row, int s, int fg) {
  return *(const short8*)&base[row * 64 + ((((s << 2) | fg) ^ (row & 7)) << 3)];
}

DEV f32x4 mfma16(short8 a, short8 b, f32x4 c) {
  return __builtin_amdgcn_mfma_f32_16x16x32_bf16(a, b, c, 0, 0, 0);
}

template <bool RELU, int STORE>
__launch_bounds__(512, 2)
__global__ void gemm8_k(unsigned char* wsb,
                        size_t aoff0, size_t boff0,
                        const float* __restrict__ bias,
                        size_t ooff0, float* __restrict__ optr,
                        int M, int N, int K, int gx, int gxy, int grp) {
  __shared__ alignas(16) short lds[10 * CH];

  unsigned char* ws = wsbase(wsb);
  const int tid = threadIdx.x;
  const int lane = tid & 63;
  const int wave = tid >> 6;
  const int wm = (wave >> 2) << 7;   // 0 / 128
  const int wn = (wave & 3) << 6;    // 0 / 64 / 128 / 192

  const int nwg = gridDim.x;
  const int q8 = nwg >> 3;
  const int id = (blockIdx.x & 7) * q8 + (blockIdx.x >> 3);
  const int bz = id / gxy;
  const int rem = id - bz * gxy;
  int by, bx;
  raster2d(rem, gx, grp, by, bx);
  const int brow = by << 8;
  const int bcol = bx << 8;

  const short* A0 = (const short*)(ws + aoff0) + (size_t)bz * M * K;
  const short* B0g = (const short*)(ws + boff0) + (size_t)bz * N * K;

  size_t aSrc[2][2], bSrc[2][2];
#pragma unroll
  for (int h = 0; h < 2; ++h) {
    const int G = tid + h * 512;
    const int r = G >> 3, c = G & 7;
#pragma unroll
    for (int qq = 0; qq < 2; ++qq) {
      aSrc[qq][h] = (size_t)(brow + qq * 128 + r) * K + (size_t)((c ^ (r & 7)) << 3);
      bSrc[qq][h] = (size_t)(bcol + qq * 128 + r) * K + (size_t)((c ^ (r & 7)) << 3);
    }
  }
  const int ldst0 = tid << 3;

  auto issueA = [&](int slot, int qq, int tt) {
    short* dst = &lds[slot + qq * CH];
    const size_t ka = (size_t)tt * 64;
    gl16(A0 + aSrc[qq][0] + ka, dst + ldst0);
    gl16(A0 + aSrc[qq][1] + ka, dst + ldst0 + CH / 2);
  };
  auto issueB = [&](int slot, int qq, int tt) {
    short* dst = &lds[slot + qq * CH];
    const size_t ka = (size_t)tt * 64;
    gl16(B0g + bSrc[qq][0] + ka, dst + ldst0);
    gl16(B0g + bSrc[qq][1] + ka, dst + ldst0 + CH / 2);
  };

  const int nt = K / 64;
  const int fr = lane & 15;
  const int fg = lane >> 4;

  f32x4 acc[8][4] = {};

  issueA(0, 0, 0); issueA(0, 1, 0);
  issueB(6 * CH, 0, 0); issueB(6 * CH, 1, 0);
  if (nt > 1) {
    issueA(2 * CH, 0, 1); issueA(2 * CH, 1, 1);
    issueB(8 * CH, 0, 1); issueB(8 * CH, 1, 1);
    asm volatile("s_waitcnt vmcnt(8)" ::: "memory");
  } else {
    asm volatile("s_waitcnt vmcnt(0)" ::: "memory");
  }
  __builtin_amdgcn_s_barrier();

  for (int t = 0; t < nt; ++t) {
    const short* aBase = &lds[(t % 3) * (2 * CH)];
    const short* bBase = &lds[6 * CH + (t & 1) * (2 * CH)];
    const int sA2 = ((t + 2) % 3) * (2 * CH);
    const int sB  = 6 * CH + (t & 1) * (2 * CH);
    const bool pf = (t + 2 < nt);
    short8 bfr[4][2], av[4][2];

    if (pf) { issueA(sA2, 0, t + 2); issueA(sA2, 1, t + 2); }
#pragma unroll
    for (int j = 0; j < 4; ++j) {
      bfr[j][0] = read_frag1(bBase, wn + j * 16 + fr, 0, fg);
      bfr[j][1] = read_frag1(bBase, wn + j * 16 + fr, 1, fg);
    }
#pragma unroll
    for (int i = 0; i < 4; ++i) {
      av[i][0] = read_frag1(aBase, wm + i * 16 + fr, 0, fg);
      av[i][1] = read_frag1(aBase, wm + i * 16 + fr, 1, fg);
    }
    __builtin_amdgcn_s_setprio(1);
#pragma unroll
    for (int i = 0; i < 4; ++i)
#pragma unroll
      for (int j = 0; j < 4; ++j) {
        acc[i][j] = mfma16(av[i][0], bfr[j][0], acc[i][j]);
        acc[i][j] = mfma16(av[i][1], bfr[j][1], acc[i][j]);
      }
    __builtin_amdgcn_s_setprio(0);
    __builtin_amdgcn_s_barrier();

    asm volatile("" ::: "memory");
    if (pf) { issueB(sB, 0, t + 2); issueB(sB, 1, t + 2); }
#pragma unroll
    for (int i = 0; i < 4; ++i) {
      av[i][0] = read_frag1(aBase, wm + 64 + i * 16 + fr, 0, fg);
      av[i][1] = read_frag1(aBase, wm + 64 + i * 16 + fr, 1, fg);
    }
    __builtin_amdgcn_s_setprio(1);
#pragma unroll
    for (int i = 0; i < 4; ++i)
#pragma unroll
      for (int j = 0; j < 4; ++j) {
        acc[4 + i][j] = mfma16(av[i][0], bfr[j][0], acc[4 + i][j]);
        acc[4 + i][j] = mfma16(av[i][1], bfr[j][1], acc[4 + i][j]);
      }
    __builtin_amdgcn_s_setprio(0);
    if (pf) {
      asm volatile("s_waitcnt vmcnt(8)" ::: "memory");
    } else {
      asm volatile("s_waitcnt vmcnt(0)" ::: "memory");
    }
    __builtin_amdgcn_s_barrier();
  }

  // ---- epilogue ----
  const int fq4 = (lane >> 4) << 2;
  if constexpr (STORE == 1) {
    short* Oh = (short*)(ws + ooff0);
    __builtin_amdgcn_s_barrier();
#pragma unroll
    for (int i = 0; i < 8; ++i) {
      const int rl = wm + i * 16 + fq4;
#pragma unroll
      for (int j = 0; j < 4; ++j) {
        const int cl = wn + j * 16 + fr;
        const float bv = bias ? bias[bcol + cl] : 0.0f;
#pragma unroll
        for (int e = 0; e < 4; ++e) {
          float u = acc[i][j][e] + bv;
          if (RELU) u = fmaxf(u, 0.0f);
          lds[(rl + e) * 264 + cl] = f2bf(u);
        }
      }
    }
    __builtin_amdgcn_s_barrier();
#pragma unroll
    for (int gi = 0; gi < 16; ++gi) {
      const int g = gi * 512 + tid;
      const int row = g >> 5, cg = g & 31;
      const short8 v = *(const short8*)&lds[row * 264 + cg * 8];
      nts(v, (short8*)&Oh[(size_t)(brow + row) * N + bcol + cg * 8]);
    }
  } else {
    float* Op = optr + (size_t)bz * M * N;
    float* ldsf = (float*)lds;
#pragma unroll
    for (int h = 0; h < 2; ++h) {
      __builtin_amdgcn_s_barrier();
      if ((wm & 128) == (h << 7)) {
#pragma unroll
        for (int i = 0; i < 8; ++i) {
          const int rp = (wm & 127) + i * 16 + fq4;
#pragma unroll
          for (int j = 0; j < 4; ++j) {
            const int cl = wn + j * 16 + fr;
#pragma unroll
            for (int e = 0; e < 4; ++e)
              ldsf[(rp + e) * 258 + cl] = acc[i][j][e];
          }
        }
      }
      __builtin_amdgcn_s_barrier();
#pragma unroll
      for (int gi = 0; gi < 16; ++gi) {
        const int g = gi * 512 + tid;
        const int tr = g >> 6, tc4 = (g & 63) << 2;
        const f32x4 v = *(const f32x4*)&ldsf[tr * 258 + tc4];
        nts(v, (f32x4*)&Op[(size_t)(brow + h * 128 + tr) * N + bcol + tc4]);
      }
    }
  }
}

// ---------------------------------------------------------------------------
// row softmax over ST rows (axis-1 softmax of scores), output bf16 probs^T
// ---------------------------------------------------------------------------
__launch_bounds__(256)
__global__ void softmax_rows_k(unsigned char* wsb, size_t st, size_t pt) {
  constexpr int S = 2048;
  unsigned char* ws = wsbase(wsb);
  const f32x4* row = (const f32x4*)((const float*)(ws + st) + (size_t)blockIdx.x * S);
  short4v* out = (short4v*)((short*)(ws + pt) + (size_t)blockIdx.x * S);
  const int tid = threadIdx.x, lane = tid & 63, wv = tid >> 6;
  const f32x4 a = ntl(&row[tid]);
  const f32x4 b = ntl(&row[tid + 256]);
  float m = fmaxf(fmaxf(fmaxf(a[0], a[1]), fmaxf(a[2], a[3])),
                  fmaxf(fmaxf(b[0], b[1]), fmaxf(b[2], b[3])));
#pragma unroll
  for (int o = 32; o; o >>= 1) m = fmaxf(m, __shfl_xor(m, o));
  __shared__ float rb[8];
  if (lane == 0) rb[wv] = m;
  __syncthreads();
  m = fmaxf(fmaxf(rb[0], rb[1]), fmaxf(rb[2], rb[3]));
  float e[8];
  float s = 0.0f;
#pragma unroll
  for (int q = 0; q < 4; ++q) { e[q] = expf(a[q] - m); s += e[q]; }
#pragma unroll
  for (int q = 0; q < 4; ++q) { e[4 + q] = expf(b[q] - m); s += e[4 + q]; }
#pragma unroll
  for (int o = 32; o; o >>= 1) s += __shfl_xor(s, o);
  if (lane == 0) rb[4 + wv] = s;
  __syncthreads();
  s = rb[4] + rb[5] + rb[6] + rb[7];
  const float inv = 1.0f / s;
  short4v o1, o2;
#pragma unroll
  for (int q = 0; q < 4; ++q) { o1[q] = f2bf(e[q] * inv); o2[q] = f2bf(e[4 + q] * inv); }
  nts(o1, &out[tid]);
  nts(o2, &out[tid + 256]);
}

// ---------------------------------------------------------------------------
extern "C" void kernel_launch(void* const* d_in, const int* in_sizes, int n_in,
                              void* d_out, int out_size, void* d_ws, size_t ws_size,
                              hipStream_t stream) {
  const float* x   = (const float*)d_in[0];
  const float* qw1 = (const float*)d_in[1];
  const float* qb1 = (const float*)d_in[2];
  const float* qw2 = (const float*)d_in[3];
  const float* qb2 = (const float*)d_in[4];
  const float* kw1 = (const float*)d_in[5];
  const float* kb1 = (const float*)d_in[6];
  const float* kw2 = (const float*)d_in[7];
  const float* kb2 = (const float*)d_in[8];
  const float* vw1 = (const float*)d_in[9];
  const float* vb1 = (const float*)d_in[10];
  const float* vw2 = (const float*)d_in[11];
  const float* vb2 = (const float*)d_in[12];
  float* out = (float*)d_out;
  unsigned char* wsb = (ws_size >= WS_TOTAL) ? (unsigned char*)d_ws : nullptr;
  unsigned char* wsr;
  if (wsb) wsr = wsb;
  else { hipError_t e = hipGetSymbolAddress((void**)&wsr, HIP_SYMBOL(g_ws)); (void)e; }

  const int M = BB * SS;  // 8192
  dim3 blk(512);
  dim3 tb(32, 8);

  // x -> i8 2-level (Q/K MLP1) and bf16 hi (V MLP1)
  quant_x_k<<<8192, 256, 0, stream>>>(x, wsb, OFF_XA1, OFF_XA2, OFF_XS);
  cast_hi_k<<<4096, 256, 0, stream>>>(x, wsb, OFF_XH, NX / 4);

  // ================= Q path (all i8) =================
  hipMemsetAsync(wsr + OFF_CM, 0, 32768, stream);
  colmax_k<<<dim3(HHID / 256, DD / 128), 256, 0, stream>>>(qw1, wsb, OFF_CM, DD, HHID);
  scalefix_k<<<32, 256, 0, stream>>>(wsb, OFF_CM, HHID);
  transpose_quant_k<<<dim3(HHID / 32, DD / 32), tb, 0, stream>>>(qw1, wsb, OFF_WA1, OFF_WA2, OFF_CM, DD, HHID);
  gemm_i8_k<true, 0><<<2048, blk, 0, stream>>>(wsb, OFF_XA1, OFF_XA2, OFF_WA1, OFF_WA2,
                                               OFF_XS, OFF_CM, qb1, OFF_HH, OFF_HL,
                                               M, HHID, DD, 32, 2048, 8);
  rowquant_k<<<8192, 1024, 0, stream>>>(wsb, OFF_HH, OFF_HL, OFF_HA1, OFF_HA2, OFF_HS, HHID);
  hipMemsetAsync(wsr + OFF_CM, 0, 32768, stream);
  colmax_k<<<dim3(DD / 256, HHID / 128), 256, 0, stream>>>(qw2, wsb, OFF_CM, HHID, DD);
  scalefix_k<<<8, 256, 0, stream>>>(wsb, OFF_CM, DD);
  transpose_quant_k<<<dim3(DD / 32, HHID / 32), tb, 0, stream>>>(qw2, wsb, OFF_WA1, OFF_WA2, OFF_CM, HHID, DD);
  gemm_i8_k<false, 0><<<512, blk, 0, stream>>>(wsb, OFF_HA1, OFF_HA2, OFF_WA1, OFF_WA2,
                                               OFF_HS, OFF_CM, qb2, OFF_QKH, OFF_QKL,
                                               M, DD, HHID, 8, 512, 8);
  rowquant_k<<<8192, 256, 0, stream>>>(wsb, OFF_QKH, OFF_QKL, OFF_QA1, OFF_QA2, OFF_QS, DD);

  // ================= K path (all i8) =================
  hipMemsetAsync(wsr + OFF_CM, 0, 32768, stream);
  colmax_k<<<dim3(HHID / 256, DD / 128), 256, 0, stream>>>(kw1, wsb, OFF_CM, DD, HHID);
  scalefix_k<<<32, 256, 0, stream>>>(wsb, OFF_CM, HHID);
  transpose_quant_k<<<dim3(HHID / 32, DD / 32), tb, 0, stream>>>(kw1, wsb, OFF_WA1, OFF_WA2, OFF_CM, DD, HHID);
  gemm_i8_k<true, 0><<<2048, blk, 0, stream>>>(wsb, OFF_XA1, OFF_XA2, OFF_WA1, OFF_WA2,
                                               OFF_XS, OFF_CM, kb1, OFF_HH, OFF_HL,
                                               M, HHID, DD, 32, 2048, 8);
  rowquant_k<<<8192, 1024, 0, stream>>>(wsb, OFF_HH, OFF_HL, OFF_HA1, OFF_HA2, OFF_HS, HHID);
  hipMemsetAsync(wsr + OFF_CM, 0, 32768, stream);
  colmax_k<<<dim3(DD / 256, HHID / 128), 256, 0, stream>>>(kw2, wsb, OFF_CM, HHID, DD);
  scalefix_k<<<8, 256, 0, stream>>>(wsb, OFF_CM, DD);
  transpose_quant_k<<<dim3(DD / 32, HHID / 32), tb, 0, stream>>>(kw2, wsb, OFF_WA1, OFF_WA2, OFF_CM, HHID, DD);
  gemm_i8_k<false, 0><<<512, blk, 0, stream>>>(wsb, OFF_HA1, OFF_HA2, OFF_WA1, OFF_WA2,
                                               OFF_HS, OFF_CM, kb2, OFF_QKH, OFF_QKL,
                                               M, DD, HHID, 8, 512, 8);
  rowquant_k<<<8192, 256, 0, stream>>>(wsb, OFF_QKH, OFF_QKL, OFF_KA1, OFF_KA2, OFF_KS, DD);

  // ================= V path (plain bf16) =================
  transpose_cast_k<<<dim3(HHID / 32, DD / 32), tb, 0, stream>>>(vw1, wsb, OFF_WHV, DD, HHID);
  gemm8_k<true, 1><<<1024, blk, 0, stream>>>(
      wsb, OFF_XH, OFF_WHV, vb1, OFF_HH, nullptr, M, HHID, DD, 32, 1024, 4);
  transpose_cast_k<<<dim3(DD / 32, HHID / 32), tb, 0, stream>>>(vw2, wsb, OFF_WHV, HHID, DD);
  gemm8_k<false, 1><<<256, blk, 0, stream>>>(
      wsb, OFF_HH, OFF_WHV, vb2, OFF_V, nullptr, M, DD, HHID, 8, 256, 4);

  // ---- scores^T (i8, batched): ST[t][s] per batch ----
  gemm_i8_k<false, 2><<<512, blk, 0, stream>>>(wsb, OFF_QA1, OFF_QA2, OFF_KA1, OFF_KA2,
                                               OFF_QS, OFF_KS, nullptr, OFF_ST, 0,
                                               SS, SS, DD, 8, 128, 8);

  // ---- softmax over axis 1 == row softmax of ST; writes bf16 probs^T ----
  softmax_rows_k<<<BB * SS, 256, 0, stream>>>(wsb, OFF_ST, OFF_PT);

  // ---- out = V @ probs  (B^T = probs^T), fp32 to d_out ----
  gemm8_k<false, 3><<<256, blk, 0, stream>>>(
      wsb, OFF_V, OFF_PT, nullptr, 0, out, SS, SS, DD, 8, 64, 4);
}